// Round 12
// baseline (491.247 us; speedup 1.0000x reference)
//
#include <hip/hip_runtime.h>
#include <math.h>

#define NB 2
#define CIN 64
#define H0 96
#define W0 96
#define HH 192
#define WW 192
#define LL (HH*WW)        // 36864
#define NHASH 4
#define CHK 144
#define NCHK 256          // LL/CHK
#define CE 16
#define NBUCK 128
#define SEGL 576
#define NSEG 64           // LL/SEGL
#define PW 194            // padded width/height
#define PS ((size_t)NB*PW*PW*64)   // shorts per split plane

// ---- attention LDS layout (bytes) ----
#define P_ROWB   72
#define PST_SZB  10368
#define LKI_SZB  1728
#define V6_ROWB  72                 // 64B data (32 j bf16) + 8B pad; 18 dwords
#define V6_BUF   (64*V6_ROWB)       // 4608
#define LDS_A6   (PST_SZB + LKI_SZB + 2*V6_BUF)   // 21312 -> 3 blocks/CU
#define CONV_LDS (2*4*66*64*2)      // 67584

typedef __attribute__((ext_vector_type(8))) short short8_t;
typedef __attribute__((ext_vector_type(4))) float f32x4;
union FragU { unsigned int u[4]; int4 i; short8_t s; };

__device__ __forceinline__ unsigned int cvtpk_bf16(float a, float b){
  unsigned int r;
  asm("v_cvt_pk_bf16_f32 %0, %1, %2" : "=v"(r) : "v"(a), "v"(b));
  return r;
}
__device__ __forceinline__ float bfl(unsigned int u){ return __uint_as_float(u << 16); }
__device__ __forceinline__ float bfh(unsigned int u){ return __uint_as_float(u & 0xffff0000u); }

// ---------------- zero borders of the 4 split planes -------------------------
__global__ __launch_bounds__(256) void k_zerob(unsigned short* pA, unsigned short* pB){
  const int cid = blockIdx.x*256 + threadIdx.x;
  if (cid >= 4*2*772*8) return;
  const int chunk = cid & 7;
  int cell = cid >> 3;
  const int plane = cell / (2*772); cell -= plane*(2*772);
  const int n = cell / 772; int b = cell - n*772;
  int ypad, xpad;
  if (b < 194){ ypad = 0; xpad = b; }
  else if (b < 388){ ypad = 193; xpad = b-194; }
  else if (b < 580){ ypad = b-388+1; xpad = 0; }
  else { ypad = b-580+1; xpad = 193; }
  unsigned short* base = (plane < 2 ? pA : pB) + (size_t)(plane & 1)*PS;
  *(uint4*)(base + (((size_t)n*PW + ypad)*PW + xpad)*64 + chunk*8) =
      make_uint4(0u,0u,0u,0u);
}

// ---------------- bicubic 2x upsample -> split padded NLC --------------------
__global__ __launch_bounds__(256) void k_upsample2(const float* __restrict__ x,
    unsigned short* __restrict__ oh, unsigned short* __restrict__ ol){
  __shared__ unsigned int pk[64][65];
  const int t = threadIdx.x;
  const int bx = blockIdx.x, oy = blockIdx.y, n = blockIdx.z;
  const int oxl = t & 63, cq = t >> 6;
  const int ox = bx*64 + oxl;
  const int i = oy >> 1, a = oy & 1;
  const int j = ox >> 1, b = ox & 1;
  const float e0=-0.03515625f, e1=0.26171875f, e2=0.87890625f, e3=-0.10546875f;
  float wy[4], wx[4]; int ty[4], tx[4];
  if (a){ wy[0]=e3; wy[1]=e2; wy[2]=e1; wy[3]=e0; } else { wy[0]=e0; wy[1]=e1; wy[2]=e2; wy[3]=e3; }
  if (b){ wx[0]=e3; wx[1]=e2; wx[2]=e1; wx[3]=e0; } else { wx[0]=e0; wx[1]=e1; wx[2]=e2; wx[3]=e3; }
  const int offy = a ? -1 : -2, offx = b ? -1 : -2;
  #pragma unroll
  for (int k=0;k<4;k++){
    int u = i + offy + k; ty[k] = u<0?0:(u>H0-1?H0-1:u);
    int s = j + offx + k; tx[k] = s<0?0:(s>W0-1?W0-1:s);
  }
  for (int ci = cq*16; ci < cq*16+16; ++ci){
    const float* xp = x + ((size_t)n*CIN + ci)*(H0*W0);
    float s = 0.f;
    #pragma unroll
    for (int ky=0;ky<4;ky++){
      const float* row = xp + ty[ky]*W0;
      float rs = 0.f;
      rs = fmaf(wx[0], row[tx[0]], rs);
      rs = fmaf(wx[1], row[tx[1]], rs);
      rs = fmaf(wx[2], row[tx[2]], rs);
      rs = fmaf(wx[3], row[tx[3]], rs);
      s = fmaf(wy[ky], rs, s);
    }
    unsigned int hu = cvtpk_bf16(s, s);
    unsigned int lu = cvtpk_bf16(s - bfl(hu), 0.f);
    pk[oxl][ci] = (hu & 0xffffu) | (lu << 16);
  }
  __syncthreads();
  const size_t rowb = (((size_t)n*PW + oy+1)*PW + bx*64 + 1)*64;
  for (int e = t; e < 1024; e += 256){
    const int plane = e >> 9, r2 = e & 511;
    const int ox2 = r2 >> 3, c8 = r2 & 7;
    const int xpad = bx*64 + ox2 + 1;
    const int grp = (c8 ^ (xpad & 7))*8;
    unsigned int a0=pk[ox2][grp+0], a1=pk[ox2][grp+1], a2=pk[ox2][grp+2], a3=pk[ox2][grp+3];
    unsigned int a4=pk[ox2][grp+4], a5=pk[ox2][grp+5], a6=pk[ox2][grp+6], a7=pk[ox2][grp+7];
    uint4 wv;
    if (plane == 0){
      wv.x = (a0&0xffffu)|(a1<<16); wv.y = (a2&0xffffu)|(a3<<16);
      wv.z = (a4&0xffffu)|(a5<<16); wv.w = (a6&0xffffu)|(a7<<16);
    } else {
      wv.x = (a0>>16)|(a1&0xffff0000u); wv.y = (a2>>16)|(a3&0xffff0000u);
      wv.z = (a4>>16)|(a5&0xffff0000u); wv.w = (a6>>16)|(a7&0xffff0000u);
    }
    *(uint4*)((plane ? ol : oh) + rowb + (size_t)ox2*64 + c8*8) = wv;
  }
}

// ---------------- weight prep: fp32 OIHW -> bf16x2 frag layout ---------------
__global__ __launch_bounds__(256) void k_prepw(const float* __restrict__ w,
    unsigned short* __restrict__ wsT, int CO){
  int idx = blockIdx.x*256 + threadIdx.x;
  if (idx >= CO*64*9) return;
  int tap = idx % 9; int rem = idx / 9;
  int ci = rem % 64; int co = rem / 64;
  float v = w[(size_t)(co*64 + ci)*9 + tap];
  unsigned int hu = cvtpk_bf16(v, v) & 0xffffu;
  float hf = bfl(hu);
  unsigned int lu = cvtpk_bf16(v - hf, 0.f) & 0xffffu;
  int half = ci >> 5, kg = (ci >> 3) & 3, e = ci & 7;
  size_t base = ((size_t)(tap*2 + half)*2)*CO*32 + ((size_t)co*4 + kg)*8 + e;
  wsT[base]         = (unsigned short)hu;
  wsT[base + (size_t)CO*32] = (unsigned short)lu;
}

// ---------------- 3x3 conv via MFMA, bf16x3; pre-split padded-NLC input ------
template<int CO, int OMODE>
__global__ __launch_bounds__(256) void k_conv3s(const unsigned short* __restrict__ inh,
    const unsigned short* __restrict__ inl, const unsigned short* __restrict__ wsT,
    const float* __restrict__ bias, unsigned short* __restrict__ outh,
    unsigned short* __restrict__ outl, float* __restrict__ outf){
  extern __shared__ char cvsm[];
  unsigned short (*inH)[66][64] = (unsigned short (*)[66][64])cvsm;
  unsigned short (*inL)[66][64] = (unsigned short (*)[66][64])(cvsm + 33792);
  const int t = threadIdx.x;
  const int bx = blockIdx.x, by = blockIdx.y, n = blockIdx.z;
  const int y0 = by*2, x0 = bx*64;
  const int l = t & 63, w = t >> 6;
  const int lq = l & 15, kg = l >> 4;

  const size_t gbase = (((size_t)n*PW + y0)*PW + x0)*64;
  for (int e = t; e < 4224; e += 256){
    const int plane = (e >= 2112);
    const int rem = e - plane*2112;
    const int row = rem / 528;
    const int cw = rem - row*528;
    const unsigned short* src = (plane ? inl : inh) + gbase + (size_t)row*(PW*64) + cw*8;
    *(uint4*)(cvsm + plane*33792 + row*8448 + cw*16) = *(const uint4*)src;
  }
  __syncthreads();

  constexpr int NCT = CO/16;
  f32x4 acc0[NCT], acc1[NCT];
  #pragma unroll
  for (int c=0;c<NCT;c++){ acc0[c] = (f32x4){0.f,0.f,0.f,0.f}; acc1[c] = acc0[c]; }
  const unsigned short* wlane = wsT + (size_t)lq*32 + (size_t)kg*8;

  #pragma unroll
  for (int tap=0; tap<9; ++tap){
    const int ky = tap/3, kx = tap - ky*3;
    const int col = w*16 + lq + kx;
    #pragma unroll
    for (int half=0; half<2; ++half){
      const int sci = ((((half<<2) | kg) ^ (col & 7)) << 3);
      FragU Bh0, Bl0, Bh1, Bl1;
      Bh0.i = *(const int4*)&inH[ky  ][col][sci];
      Bl0.i = *(const int4*)&inL[ky  ][col][sci];
      Bh1.i = *(const int4*)&inH[ky+1][col][sci];
      Bl1.i = *(const int4*)&inL[ky+1][col][sci];
      const unsigned short* wth = wlane + (size_t)((tap*2+half)*2)*CO*32;
      #pragma unroll
      for (int ct=0; ct<NCT; ++ct){
        FragU Ah, Al;
        Ah.i = *(const int4*)(wth + ct*512);
        Al.i = *(const int4*)(wth + CO*32 + ct*512);
        acc0[ct] = __builtin_amdgcn_mfma_f32_16x16x32_bf16(Ah.s, Bl0.s, acc0[ct], 0,0,0);
        acc0[ct] = __builtin_amdgcn_mfma_f32_16x16x32_bf16(Al.s, Bh0.s, acc0[ct], 0,0,0);
        acc0[ct] = __builtin_amdgcn_mfma_f32_16x16x32_bf16(Ah.s, Bh0.s, acc0[ct], 0,0,0);
        acc1[ct] = __builtin_amdgcn_mfma_f32_16x16x32_bf16(Ah.s, Bl1.s, acc1[ct], 0,0,0);
        acc1[ct] = __builtin_amdgcn_mfma_f32_16x16x32_bf16(Al.s, Bh1.s, acc1[ct], 0,0,0);
        acc1[ct] = __builtin_amdgcn_mfma_f32_16x16x32_bf16(Ah.s, Bh1.s, acc1[ct], 0,0,0);
      }
    }
  }

  const int px = x0 + w*16 + lq;
  const int xpad = px + 1;
  const int xg = xpad & 7;
  if constexpr (OMODE == 2){
    #pragma unroll
    for (int r=0; r<4; ++r){
      const int co = kg*4 + r;
      const float bv = bias[co];
      outf[((size_t)n*LL + (size_t)(y0  )*WW + px)*16 + co] = acc0[0][r] + bv;
      outf[((size_t)n*LL + (size_t)(y0+1)*WW + px)*16 + co] = acc1[0][r] + bv;
    }
  } else {
    #pragma unroll
    for (int ct=0; ct<NCT; ++ct){
      const int ci = ct*16 + kg*4;
      const int sgrp = (ct*2 + (kg>>1)) ^ xg;
      #pragma unroll
      for (int row=0; row<2; ++row){
        const f32x4& A = row ? acc1[ct] : acc0[ct];
        float v0 = fmaxf(A[0] + bias[ci+0], 0.f);
        float v1 = fmaxf(A[1] + bias[ci+1], 0.f);
        float v2 = fmaxf(A[2] + bias[ci+2], 0.f);
        float v3 = fmaxf(A[3] + bias[ci+3], 0.f);
        const unsigned int h0 = cvtpk_bf16(v0, v1);
        const unsigned int h1 = cvtpk_bf16(v2, v3);
        const unsigned int l0 = cvtpk_bf16(v0 - bfl(h0), v1 - bfh(h0));
        const unsigned int l1 = cvtpk_bf16(v2 - bfl(h1), v3 - bfh(h1));
        const size_t off = (((size_t)n*PW + (y0+row+1))*PW + xpad)*64 + sgrp*8 + (kg&1)*4;
        *(uint2*)(outh + off) = make_uint2(h0, h1);
        *(uint2*)(outl + off) = make_uint2(l0, l1);
        if constexpr (OMODE == 1){
          *(float4*)&outf[(((size_t)n*LL + (size_t)(y0+row)*WW + px)*64) + ci] =
              make_float4(v0, v1, v2, v3);
        }
      }
    }
  }
}

// ---------------- 1x1 conv (ye), x2 in fp32-NLC, out bf16 --------------------
__global__ __launch_bounds__(256) void k_conv1x1(const float* __restrict__ x2,
    const float* __restrict__ wa, const float* __restrict__ ba,
    unsigned short* __restrict__ yeB){
  __shared__ float xs[64][65];
  __shared__ float wts[64][65];
  const int t = threadIdx.x;
  const int n = blockIdx.y;
  const int l0 = blockIdx.x*64;
  for (int e=t; e<4096; e+=256){
    int lv = e >> 6, ci = e & 63;
    xs[ci][lv]  = x2[((size_t)n*LL + l0 + lv)*64 + ci];
    wts[ci][lv] = wa[(size_t)lv*64 + ci];
  }
  __syncthreads();
  const int l = t & 63, cq = t >> 6;
  float acc[16];
  #pragma unroll
  for (int i=0;i<16;i++) acc[i] = ba[cq*16+i];
  for (int ci=0; ci<64; ci++){
    float xv = xs[ci][l];
    #pragma unroll
    for (int i=0;i<16;i++) acc[i] = fmaf(xv, wts[ci][cq*16+i], acc[i]);
  }
  unsigned int wds[8];
  #pragma unroll
  for (int i=0;i<8;i++) wds[i] = cvtpk_bf16(acc[2*i], acc[2*i+1]);
  uint4* op = (uint4*)&yeB[((size_t)n*LL + l0 + l)*64 + cq*16];
  op[0] = make_uint4(wds[0],wds[1],wds[2],wds[3]);
  op[1] = make_uint4(wds[4],wds[5],wds[6],wds[7]);
}

// ---------------- LSH codes: argmax over [rot ; -rot] ------------------------
__global__ __launch_bounds__(128) void k_codes(const float* __restrict__ xe,
    const float* __restrict__ rot, unsigned char* __restrict__ codes){
  __shared__ float rs[NHASH][64][16];
  const int t = threadIdx.x;
  for (int e=t; e<4096; e+=128){
    int f = e >> 8; int rem = e & 255;
    int h = rem >> 6; int i = rem & 63;
    rs[h][i][f] = rot[((size_t)f*NHASH + h)*64 + i];
  }
  __syncthreads();
  const int n = blockIdx.y;
  const int l = blockIdx.x*128 + t;
  float q[16];
  const float* xr = &xe[((size_t)n*LL + l)*16];
  #pragma unroll
  for (int f=0;f<16;f++) q[f] = xr[f];
  #pragma unroll
  for (int h=0;h<NHASH;h++){
    float bp = -3.0e38f, bn = -3.0e38f; int ap=0, an=0;
    for (int i=0;i<64;i++){
      float s = 0.f;
      #pragma unroll
      for (int f=0;f<16;f++) s = fmaf(q[f], rs[h][i][f], s);
      if (s > bp){ bp = s; ap = i; }
      if (-s > bn){ bn = -s; an = i; }
    }
    int code = (bp >= bn) ? ap : (64 + an);
    codes[((size_t)n*NHASH + h)*LL + l] = (unsigned char)code;
  }
}

// ---------------- stable counting sort ---------------------------------------
__global__ __launch_bounds__(256) void k_hist(const unsigned char* __restrict__ codes,
    unsigned int* __restrict__ segHist){
  __shared__ unsigned int h[NBUCK];
  const int t = threadIdx.x;
  if (t < NBUCK) h[t] = 0;
  __syncthreads();
  const int n = blockIdx.z, hh = blockIdx.y, s = blockIdx.x;
  const unsigned char* cp = codes + ((size_t)n*NHASH + hh)*LL + (size_t)s*SEGL;
  for (int e=t; e<SEGL; e+=256) atomicAdd(&h[cp[e]], 1u);
  __syncthreads();
  if (t < NBUCK)
    segHist[(((size_t)(n*NHASH+hh))*NSEG + s)*NBUCK + t] = h[t];
}

__global__ __launch_bounds__(128) void k_scan(unsigned int* __restrict__ segHist){
  __shared__ unsigned int tot[NBUCK];
  __shared__ unsigned int base[NBUCK];
  const int b = threadIdx.x;
  const size_t off = (size_t)blockIdx.x * NSEG * NBUCK;
  unsigned int run = 0;
  for (int s=0;s<NSEG;s++){
    unsigned int v = segHist[off + (size_t)s*NBUCK + b];
    segHist[off + (size_t)s*NBUCK + b] = run;
    run += v;
  }
  tot[b] = run;
  __syncthreads();
  if (b==0){ unsigned int r=0; for (int i=0;i<NBUCK;i++){ base[i]=r; r+=tot[i]; } }
  __syncthreads();
  const unsigned int bb = base[b];
  for (int s=0;s<NSEG;s++) segHist[off + (size_t)s*NBUCK + b] += bb;
}

__global__ __launch_bounds__(256) void k_rank(const unsigned char* __restrict__ codes,
    const unsigned int* __restrict__ segHist, int* __restrict__ sortPos,
    int* __restrict__ srtIdx){
  __shared__ unsigned int cw[SEGL/4];
  __shared__ unsigned int sbase[NBUCK];
  const int t = threadIdx.x;
  const int n = blockIdx.z, hh = blockIdx.y, s = blockIdx.x;
  const size_t cb = ((size_t)n*NHASH + hh)*LL + (size_t)s*SEGL;
  const unsigned int* cp32 = (const unsigned int*)(codes + cb);
  for (int e=t; e<SEGL/4; e+=256) cw[e] = cp32[e];
  if (t < NBUCK)
    sbase[t] = segHist[(((size_t)(n*NHASH+hh))*NSEG + s)*NBUCK + t];
  __syncthreads();
  const size_t ob = ((size_t)n*NHASH + hh)*LL;
  for (int e=t; e<SEGL; e+=256){
    unsigned int c = (cw[e>>2] >> ((e&3)*8)) & 0xffu;
    unsigned int mul = c * 0x01010101u;
    int cnt = 0;
    const int nw = e >> 2;
    for (int wi=0; wi<nw; wi++){
      unsigned int v = cw[wi] ^ mul;
      unsigned int t1 = (v & 0x7f7f7f7fu) + 0x7f7f7f7fu;
      unsigned int z = ~(t1 | v) & 0x80808080u;
      cnt += __popc(z);
    }
    unsigned int lastw = cw[nw];
    const int nbp = e & 3;
    for (int bp=0; bp<nbp; bp++)
      if (((lastw >> (bp*8)) & 0xffu) == c) cnt++;
    int pos = (int)sbase[c] + cnt;
    int lx = s*SEGL + e;
    sortPos[ob + lx] = pos;
    srtIdx[ob + pos] = lx;
  }
}

// ---------------- pre-gather K -----------------------------------------------
__global__ __launch_bounds__(256) void k_gatherK(const float* __restrict__ xe,
    const int* __restrict__ srtIdx, unsigned short* __restrict__ Ksrt,
    float* __restrict__ normQ){
  const int idx = blockIdx.x*256 + threadIdx.x;
  if (idx >= NB*NHASH*LL) return;
  const int n = idx / (NHASH*LL);
  const int lk = srtIdx[idx];
  const float4* xr = (const float4*)&xe[((size_t)n*LL + lk)*16];
  float4 v0 = xr[0], v1 = xr[1], v2 = xr[2], v3 = xr[3];
  float f[16] = {v0.x,v0.y,v0.z,v0.w, v1.x,v1.y,v1.z,v1.w,
                 v2.x,v2.y,v2.z,v2.w, v3.x,v3.y,v3.z,v3.w};
  float ss = 0.f;
  #pragma unroll
  for (int i=0;i<16;i++) ss = fmaf(f[i], f[i], ss);
  const float nq = sqrtf(ss);
  normQ[idx] = nq;
  const float inv = 1.f / fmaxf(nq, 5e-5f);
  #pragma unroll
  for (int i=0;i<16;i++) f[i] *= inv;
  unsigned int kh[8], klo[8];
  #pragma unroll
  for (int i=0;i<8;i++) kh[i] = cvtpk_bf16(f[2*i], f[2*i+1]);
  #pragma unroll
  for (int i=0;i<8;i++)
    klo[i] = cvtpk_bf16(f[2*i] - bfl(kh[i]), f[2*i+1] - bfh(kh[i]));
  int4* kr = (int4*)(Ksrt + (size_t)idx*32);
  kr[0] = make_int4((int)kh[0],(int)kh[1],(int)kh[2],(int)kh[3]);
  kr[1] = make_int4((int)kh[4],(int)kh[5],(int)kh[6],(int)kh[7]);
  kr[2] = make_int4((int)klo[0],(int)klo[1],(int)klo[2],(int)klo[3]);
  kr[3] = make_int4((int)klo[4],(int)klo[5],(int)klo[6],(int)klo[7]);
}

// ---------------- attention v6: per-u double-buffered V tiles ----------------
// Values/order identical to R5/R11 attn (absmax canary). LDS 21.3KB ->
// 3 blocks/CU (27/32 waves). V tile rows 72B (18 dwords) -> <=4-way conflict
// (was 8-way at 912B). One barrier per u; stage tile u+1 while computing u.
__global__ __launch_bounds__(576) void k_attn6(const unsigned short* __restrict__ yeB,
    const int* __restrict__ srtIdx, const unsigned short* __restrict__ Ksrt,
    const float* __restrict__ normQ, unsigned short* __restrict__ retS,
    float* __restrict__ bscore){
  extern __shared__ char smem[];
  char* Pst = smem;
  int* lkI  = (int*)(smem + PST_SZB);
  char* Vb  = smem + PST_SZB + LKI_SZB;   // 12096 (16B aligned), 2 x 4608

  const int t = threadIdx.x;
  const int k = blockIdx.x, hh = blockIdx.y, n = blockIdx.z;
  const size_t sb = ((size_t)n*NHASH + hh)*LL;
  const int l = t & 63, w = t >> 6;
  const int lq16 = l & 15, g = l >> 4;

  if (t < 432){
    const int c3 = t / CHK, jl = t - c3*CHK;
    const int kc = (c3==0) ? k : ((c3==1) ? ((k+NCHK-1)&(NCHK-1)) : ((k+1)&(NCHK-1)));
    lkI[t] = srtIdx[sb + (size_t)kc*CHK + jl];
  }
  __syncthreads();

  // stage V tile 0 (rows 0..31; all < 432)
  for (int e=t; e<1024; e+=576){
    const int jp = e>>6, c = e&63;
    const unsigned a = yeB[((size_t)n*LL + lkI[jp*2  ])*64 + c];
    const unsigned b = yeB[((size_t)n*LL + lkI[jp*2+1])*64 + c];
    *(unsigned*)(Vb + c*V6_ROWB + jp*4) = a | (b << 16);
  }
  const int qg = w*16 + lq16;
  const int pq = k*CHK + qg;
  FragU b1, b2;
  const unsigned short* qrow = Ksrt + (sb + pq)*32;
  b1.i = *(const int4*)(qrow + (g&1)*8);
  if (g < 2) b2.i = *(const int4*)(qrow + 16 + (g&1)*8);
  else { b2.u[0]=0u; b2.u[1]=0u; b2.u[2]=0u; b2.u[3]=0u; }
  const float nq_ = normQ[sb + pq];
  const float msc = fmaxf(nq_, 5e-5f);
  __syncthreads();

  float sum = 0.f;
  f32x4 O0 = {0.f,0.f,0.f,0.f}, O1 = O0, O2 = O0, O3 = O0;
  char* Pw = Pst + w*(16*P_ROWB);

  for (int u=0; u<14; ++u){
    char* const Vcur = Vb + (u&1)*V6_BUF;
    char* const Vnxt = Vb + ((u+1)&1)*V6_BUF;
    // stage tile u+1 (rows 32(u+1)..+31; guard phantom >=432 with zeros)
    if (u < 13){
      const int jb = 32*(u+1);
      for (int e=t; e<1024; e+=576){
        const int jp = e>>6, c = e&63;
        const int j0 = jb + jp*2;
        const unsigned a = (j0   < 432) ? (unsigned)yeB[((size_t)n*LL + lkI[j0  ])*64 + c] : 0u;
        const unsigned b = (j0+1 < 432) ? (unsigned)yeB[((size_t)n*LL + lkI[j0+1])*64 + c] : 0u;
        *(unsigned*)(Vnxt + c*V6_ROWB + jp*4) = a | (b << 16);
      }
    }
    // QK(u) + P->LDS (identical arithmetic to R11)
    #pragma unroll
    for (int sub=0; sub<2; ++sub){
      const int t27 = u*2 + sub;
      uint2 pw;
      if (t27 < 27){
        const int c3 = t27 / 9;
        const int kc = (c3==0) ? k : ((c3==1) ? ((k+NCHK-1)&(NCHK-1)) : ((k+1)&(NCHK-1)));
        const int row16 = (t27 - c3*9)*16;
        FragU a; a.i = *(const int4*)(Ksrt + (sb + (size_t)kc*CHK + row16 + lq16)*32 + g*8);
        f32x4 C = {0.f,0.f,0.f,0.f};
        C = __builtin_amdgcn_mfma_f32_16x16x32_bf16(a.s, b2.s, C, 0, 0, 0);
        C = __builtin_amdgcn_mfma_f32_16x16x32_bf16(a.s, b1.s, C, 0, 0, 0);
        const float p0 = __expf(fmaf(msc, C[0], -nq_));
        const float p1 = __expf(fmaf(msc, C[1], -nq_));
        const float p2 = __expf(fmaf(msc, C[2], -nq_));
        const float p3 = __expf(fmaf(msc, C[3], -nq_));
        sum += (p0+p1) + (p2+p3);
        pw = make_uint2(cvtpk_bf16(p0,p1), cvtpk_bf16(p2,p3));
      } else {
        pw = make_uint2(0u, 0u);
      }
      *(uint2*)(Pw + lq16*P_ROWB + sub*32 + g*8) = pw;
    }
    asm volatile("s_waitcnt lgkmcnt(0)" ::: "memory");
    __builtin_amdgcn_sched_barrier(0);
    FragU bp; bp.i = *(const int4*)(Pw + lq16*P_ROWB + g*16);
    const char* Vr = Vcur + lq16*V6_ROWB + g*16;
    FragU av;
    av.i = *(const int4*)(Vr);              O0 = __builtin_amdgcn_mfma_f32_16x16x32_bf16(av.s, bp.s, O0, 0,0,0);
    av.i = *(const int4*)(Vr + 16*V6_ROWB); O1 = __builtin_amdgcn_mfma_f32_16x16x32_bf16(av.s, bp.s, O1, 0,0,0);
    av.i = *(const int4*)(Vr + 32*V6_ROWB); O2 = __builtin_amdgcn_mfma_f32_16x16x32_bf16(av.s, bp.s, O2, 0,0,0);
    av.i = *(const int4*)(Vr + 48*V6_ROWB); O3 = __builtin_amdgcn_mfma_f32_16x16x32_bf16(av.s, bp.s, O3, 0,0,0);
    __syncthreads();   // tile u+1 ready; all reads of Vcur done before overwrite
  }
  sum += __shfl_xor(sum, 16);
  sum += __shfl_xor(sum, 32);
  const float linv = 1.f / sum;

  unsigned short* op = &retS[(sb + pq)*64];
  {
    uint2 s0 = make_uint2(cvtpk_bf16(O0[0]*linv, O0[1]*linv), cvtpk_bf16(O0[2]*linv, O0[3]*linv));
    uint2 s1 = make_uint2(cvtpk_bf16(O1[0]*linv, O1[1]*linv), cvtpk_bf16(O1[2]*linv, O1[3]*linv));
    uint2 s2 = make_uint2(cvtpk_bf16(O2[0]*linv, O2[1]*linv), cvtpk_bf16(O2[2]*linv, O2[3]*linv));
    uint2 s3 = make_uint2(cvtpk_bf16(O3[0]*linv, O3[1]*linv), cvtpk_bf16(O3[2]*linv, O3[3]*linv));
    *(uint2*)(op +  0 + g*4) = s0;
    *(uint2*)(op + 16 + g*4) = s1;
    *(uint2*)(op + 32 + g*4) = s2;
    *(uint2*)(op + 48 + g*4) = s3;
  }
  if (g == 0) bscore[sb + pq] = nq_ + logf(sum);
}

// ---------------- unsort + hash-softmax combine + residual -------------------
__global__ __launch_bounds__(256) void k_combine(const unsigned short* __restrict__ retS,
    const float* __restrict__ bscore, const int* __restrict__ sortPos,
    const float* __restrict__ x2, float* __restrict__ out){
  const int idx = blockIdx.x*256 + threadIdx.x;
  if (idx >= NB*LL) return;
  const int l = idx % LL, n = idx / LL;
  float bs[NHASH]; int pp[NHASH];
  #pragma unroll
  for (int h=0;h<NHASH;h++){
    size_t sb = ((size_t)n*NHASH + h)*LL;
    int p = sortPos[sb + l];
    pp[h] = p; bs[h] = bscore[sb + p];
  }
  float m = fmaxf(fmaxf(bs[0],bs[1]), fmaxf(bs[2],bs[3]));
  float wsum = 0.f; float wv[NHASH];
  #pragma unroll
  for (int h=0;h<NHASH;h++){ wv[h] = expf(bs[h]-m); wsum += wv[h]; }
  const float winv = 1.f / wsum;
  float o[64];
  #pragma unroll
  for (int i=0;i<64;i++) o[i]=0.f;
  #pragma unroll
  for (int h=0;h<NHASH;h++){
    const float wh = wv[h]*winv;
    const uint4* rp = (const uint4*)&retS[(((size_t)n*NHASH + h)*LL + pp[h])*64];
    #pragma unroll
    for (int i2=0;i2<8;i2++){
      uint4 v = rp[i2];
      o[i2*8+0] = fmaf(wh, bfl(v.x), o[i2*8+0]);
      o[i2*8+1] = fmaf(wh, bfh(v.x), o[i2*8+1]);
      o[i2*8+2] = fmaf(wh, bfl(v.y), o[i2*8+2]);
      o[i2*8+3] = fmaf(wh, bfh(v.y), o[i2*8+3]);
      o[i2*8+4] = fmaf(wh, bfl(v.z), o[i2*8+4]);
      o[i2*8+5] = fmaf(wh, bfh(v.z), o[i2*8+5]);
      o[i2*8+6] = fmaf(wh, bfl(v.w), o[i2*8+6]);
      o[i2*8+7] = fmaf(wh, bfh(v.w), o[i2*8+7]);
    }
  }
  const float4* xr = (const float4*)&x2[((size_t)n*LL + l)*64];
  #pragma unroll
  for (int c4=0; c4<16; ++c4){
    float4 xv = xr[c4];
    out[((size_t)n*64 + c4*4+0)*LL + l] = o[c4*4+0] + xv.x;
    out[((size_t)n*64 + c4*4+1)*LL + l] = o[c4*4+1] + xv.y;
    out[((size_t)n*64 + c4*4+2)*LL + l] = o[c4*4+2] + xv.z;
    out[((size_t)n*64 + c4*4+3)*LL + l] = o[c4*4+3] + xv.w;
  }
}

extern "C" void kernel_launch(void* const* d_in, const int* in_sizes, int n_in,
                              void* d_out, int out_size, void* d_ws, size_t ws_size,
                              hipStream_t stream){
  const float* x   = (const float*)d_in[0];
  const float* w1  = (const float*)d_in[1];
  const float* b1  = (const float*)d_in[2];
  const float* w2  = (const float*)d_in[3];
  const float* b2  = (const float*)d_in[4];
  const float* wm  = (const float*)d_in[5];
  const float* bm  = (const float*)d_in[6];
  const float* wa  = (const float*)d_in[7];
  const float* ba  = (const float*)d_in[8];
  const float* rot = (const float*)d_in[9];
  float* outp = (float*)d_out;
  char* ws = (char*)d_ws;
  const size_t FM   = (size_t)NB*CIN*HH*WW*sizeof(float);
  const size_t YEB  = (size_t)NB*LL*64*2;
  const size_t RETB = (size_t)NB*NHASH*LL*64*2;
  const size_t NHL4 = (size_t)NB*NHASH*LL*4;

  char* p = ws;
  unsigned short* yeB = (unsigned short*)p;  p += YEB;
  char* regA = p;                            p += RETB;   // retS | pairA
  float* x2  = (float*)p;                    p += FM;     // fp32 NLC64
  float* xe  = (float*)p;                    p += (size_t)NB*LL*CE*sizeof(float);
  unsigned char* codes = (unsigned char*)p;  p += (size_t)NB*NHASH*LL;
  unsigned int* segHist = (unsigned int*)p;  p += (size_t)NB*NHASH*NSEG*NBUCK*4;
  int* sortPos = (int*)p;                    p += NHL4;
  int* srtIdx  = (int*)p;                    p += NHL4;
  float* bscore = (float*)p;                 p += NHL4;
  unsigned short* wsT1 = (unsigned short*)p; p += (size_t)9*2*2*64*32*2;
  unsigned short* wsT2 = (unsigned short*)p; p += (size_t)9*2*2*64*32*2;
  unsigned short* wsTm = (unsigned short*)p; p += (size_t)9*2*2*16*32*2;
  unsigned short* Ksrt = (unsigned short*)p; p += (size_t)NB*NHASH*LL*32*2;  // | pairB
  float* normQ = (float*)p;                  p += NHL4;
  const size_t needT1 = (size_t)(p - ws);
  if (ws_size < needT1) return;

  unsigned short* retS = (unsigned short*)regA;
  unsigned short* pairA = (unsigned short*)regA;
  unsigned short* pairB = Ksrt;

  hipFuncSetAttribute((const void*)k_attn6,
                      hipFuncAttributeMaxDynamicSharedMemorySize, LDS_A6);
  hipFuncSetAttribute((const void*)k_conv3s<64,0>,
                      hipFuncAttributeMaxDynamicSharedMemorySize, CONV_LDS);
  hipFuncSetAttribute((const void*)k_conv3s<64,1>,
                      hipFuncAttributeMaxDynamicSharedMemorySize, CONV_LDS);
  hipFuncSetAttribute((const void*)k_conv3s<16,2>,
                      hipFuncAttributeMaxDynamicSharedMemorySize, CONV_LDS);

  k_prepw<<<dim3((64*64*9+255)/256), dim3(256), 0, stream>>>(w1, wsT1, 64);
  k_prepw<<<dim3((64*64*9+255)/256), dim3(256), 0, stream>>>(w2, wsT2, 64);
  k_prepw<<<dim3((16*64*9+255)/256), dim3(256), 0, stream>>>(wm, wsTm, 16);
  k_zerob<<<dim3((4*2*772*8+255)/256), dim3(256), 0, stream>>>(pairA, pairB);
  k_upsample2<<<dim3(WW/64, HH, NB), dim3(256), 0, stream>>>(x, pairA, pairA + PS);
  k_conv3s<64,0><<<dim3(3, HH/2, NB), dim3(256), CONV_LDS, stream>>>(
      pairA, pairA + PS, wsT1, b1, pairB, pairB + PS, nullptr);
  k_conv3s<64,1><<<dim3(3, HH/2, NB), dim3(256), CONV_LDS, stream>>>(
      pairB, pairB + PS, wsT2, b2, pairA, pairA + PS, x2);
  k_conv3s<16,2><<<dim3(3, HH/2, NB), dim3(256), CONV_LDS, stream>>>(
      pairA, pairA + PS, wsTm, bm, nullptr, nullptr, xe);
  k_conv1x1<<<dim3(LL/64, NB), dim3(256), 0, stream>>>(x2, wa, ba, yeB);
  k_codes<<<dim3(LL/128, NB), dim3(128), 0, stream>>>(xe, rot, codes);
  k_hist<<<dim3(NSEG, NHASH, NB), dim3(256), 0, stream>>>(codes, segHist);
  k_scan<<<dim3(NB*NHASH), dim3(128), 0, stream>>>(segHist);
  k_rank<<<dim3(NSEG, NHASH, NB), dim3(256), 0, stream>>>(codes, segHist, sortPos, srtIdx);
  k_gatherK<<<dim3((NB*NHASH*LL+255)/256), dim3(256), 0, stream>>>(xe, srtIdx, Ksrt, normQ);
  k_attn6<<<dim3(NCHK, NHASH, NB), dim3(576), LDS_A6, stream>>>(
      yeB, srtIdx, Ksrt, normQ, retS, bscore);
  k_combine<<<dim3((NB*LL+255)/256), dim3(256), 0, stream>>>(retS, bscore, sortPos, x2, outp);
}

// Round 13
// 349.137 us; speedup vs baseline: 1.4070x; 1.4070x over previous
//
#include <hip/hip_runtime.h>
#include <math.h>

#define NB 2
#define CIN 64
#define H0 96
#define W0 96
#define HH 192
#define WW 192
#define LL (HH*WW)        // 36864
#define NHASH 4
#define CHK 144
#define NCHK 256          // LL/CHK
#define CE 16
#define NBUCK 128
#define SEGL 576
#define NSEG 64           // LL/SEGL
#define PW 194            // padded width/height
#define PS ((size_t)NB*PW*PW*64)   // shorts per split plane

// ---- attention LDS layout (bytes) ----
#define K_ROWB   80
#define V_ROWB   912
#define P_ROWB   72
#define VT_SZB   58368
#define PST_SZB  10368
#define LKI_SZB  1728
#define LDS_T1   (VT_SZB + PST_SZB + LKI_SZB)   // 70464
#define CONV_LDS (2*4*66*64*2)                  // 67584

typedef __attribute__((ext_vector_type(8))) short short8_t;
typedef __attribute__((ext_vector_type(4))) float f32x4;
union FragU { unsigned int u[4]; int4 i; short8_t s; };

__device__ __forceinline__ unsigned int cvtpk_bf16(float a, float b){
  unsigned int r;
  asm("v_cvt_pk_bf16_f32 %0, %1, %2" : "=v"(r) : "v"(a), "v"(b));
  return r;
}
__device__ __forceinline__ float bfl(unsigned int u){ return __uint_as_float(u << 16); }
__device__ __forceinline__ float bfh(unsigned int u){ return __uint_as_float(u & 0xffff0000u); }

// ---------------- zero borders of the 4 split planes -------------------------
__global__ __launch_bounds__(256) void k_zerob(unsigned short* pA, unsigned short* pB){
  const int cid = blockIdx.x*256 + threadIdx.x;
  if (cid >= 4*2*772*8) return;
  const int chunk = cid & 7;
  int cell = cid >> 3;
  const int plane = cell / (2*772); cell -= plane*(2*772);
  const int n = cell / 772; int b = cell - n*772;
  int ypad, xpad;
  if (b < 194){ ypad = 0; xpad = b; }
  else if (b < 388){ ypad = 193; xpad = b-194; }
  else if (b < 580){ ypad = b-388+1; xpad = 0; }
  else { ypad = b-580+1; xpad = 193; }
  unsigned short* base = (plane < 2 ? pA : pB) + (size_t)(plane & 1)*PS;
  *(uint4*)(base + (((size_t)n*PW + ypad)*PW + xpad)*64 + chunk*8) =
      make_uint4(0u,0u,0u,0u);
}

// ---------------- bicubic 2x upsample -> split padded NLC --------------------
__global__ __launch_bounds__(256) void k_upsample2(const float* __restrict__ x,
    unsigned short* __restrict__ oh, unsigned short* __restrict__ ol){
  __shared__ unsigned int pk[64][65];
  const int t = threadIdx.x;
  const int bx = blockIdx.x, oy = blockIdx.y, n = blockIdx.z;
  const int oxl = t & 63, cq = t >> 6;
  const int ox = bx*64 + oxl;
  const int i = oy >> 1, a = oy & 1;
  const int j = ox >> 1, b = ox & 1;
  const float e0=-0.03515625f, e1=0.26171875f, e2=0.87890625f, e3=-0.10546875f;
  float wy[4], wx[4]; int ty[4], tx[4];
  if (a){ wy[0]=e3; wy[1]=e2; wy[2]=e1; wy[3]=e0; } else { wy[0]=e0; wy[1]=e1; wy[2]=e2; wy[3]=e3; }
  if (b){ wx[0]=e3; wx[1]=e2; wx[2]=e1; wx[3]=e0; } else { wx[0]=e0; wx[1]=e1; wx[2]=e2; wx[3]=e3; }
  const int offy = a ? -1 : -2, offx = b ? -1 : -2;
  #pragma unroll
  for (int k=0;k<4;k++){
    int u = i + offy + k; ty[k] = u<0?0:(u>H0-1?H0-1:u);
    int s = j + offx + k; tx[k] = s<0?0:(s>W0-1?W0-1:s);
  }
  for (int ci = cq*16; ci < cq*16+16; ++ci){
    const float* xp = x + ((size_t)n*CIN + ci)*(H0*W0);
    float s = 0.f;
    #pragma unroll
    for (int ky=0;ky<4;ky++){
      const float* row = xp + ty[ky]*W0;
      float rs = 0.f;
      rs = fmaf(wx[0], row[tx[0]], rs);
      rs = fmaf(wx[1], row[tx[1]], rs);
      rs = fmaf(wx[2], row[tx[2]], rs);
      rs = fmaf(wx[3], row[tx[3]], rs);
      s = fmaf(wy[ky], rs, s);
    }
    unsigned int hu = cvtpk_bf16(s, s);
    unsigned int lu = cvtpk_bf16(s - bfl(hu), 0.f);
    pk[oxl][ci] = (hu & 0xffffu) | (lu << 16);
  }
  __syncthreads();
  const size_t rowb = (((size_t)n*PW + oy+1)*PW + bx*64 + 1)*64;
  for (int e = t; e < 1024; e += 256){
    const int plane = e >> 9, r2 = e & 511;
    const int ox2 = r2 >> 3, c8 = r2 & 7;
    const int xpad = bx*64 + ox2 + 1;
    const int grp = (c8 ^ (xpad & 7))*8;
    unsigned int a0=pk[ox2][grp+0], a1=pk[ox2][grp+1], a2=pk[ox2][grp+2], a3=pk[ox2][grp+3];
    unsigned int a4=pk[ox2][grp+4], a5=pk[ox2][grp+5], a6=pk[ox2][grp+6], a7=pk[ox2][grp+7];
    uint4 wv;
    if (plane == 0){
      wv.x = (a0&0xffffu)|(a1<<16); wv.y = (a2&0xffffu)|(a3<<16);
      wv.z = (a4&0xffffu)|(a5<<16); wv.w = (a6&0xffffu)|(a7<<16);
    } else {
      wv.x = (a0>>16)|(a1&0xffff0000u); wv.y = (a2>>16)|(a3&0xffff0000u);
      wv.z = (a4>>16)|(a5&0xffff0000u); wv.w = (a6>>16)|(a7&0xffff0000u);
    }
    *(uint4*)((plane ? ol : oh) + rowb + (size_t)ox2*64 + c8*8) = wv;
  }
}

// ---------------- weight prep: fp32 OIHW -> bf16x2 frag layout ---------------
__global__ __launch_bounds__(256) void k_prepw(const float* __restrict__ w,
    unsigned short* __restrict__ wsT, int CO){
  int idx = blockIdx.x*256 + threadIdx.x;
  if (idx >= CO*64*9) return;
  int tap = idx % 9; int rem = idx / 9;
  int ci = rem % 64; int co = rem / 64;
  float v = w[(size_t)(co*64 + ci)*9 + tap];
  unsigned int hu = cvtpk_bf16(v, v) & 0xffffu;
  float hf = bfl(hu);
  unsigned int lu = cvtpk_bf16(v - hf, 0.f) & 0xffffu;
  int half = ci >> 5, kg = (ci >> 3) & 3, e = ci & 7;
  size_t base = ((size_t)(tap*2 + half)*2)*CO*32 + ((size_t)co*4 + kg)*8 + e;
  wsT[base]         = (unsigned short)hu;
  wsT[base + (size_t)CO*32] = (unsigned short)lu;
}

// ---------------- 3x3 conv via MFMA, bf16x3; pre-split padded-NLC input ------
// OMODE 0: split-NLC out (+relu); 1: split-NLC + fp32-NLC64 out (+relu);
// OMODE 2: fp32-NLC16 out (no relu).
template<int CO, int OMODE>
__global__ __launch_bounds__(256) void k_conv3s(const unsigned short* __restrict__ inh,
    const unsigned short* __restrict__ inl, const unsigned short* __restrict__ wsT,
    const float* __restrict__ bias, unsigned short* __restrict__ outh,
    unsigned short* __restrict__ outl, float* __restrict__ outf){
  extern __shared__ char cvsm[];
  unsigned short (*inH)[66][64] = (unsigned short (*)[66][64])cvsm;
  unsigned short (*inL)[66][64] = (unsigned short (*)[66][64])(cvsm + 33792);
  const int t = threadIdx.x;
  const int bx = blockIdx.x, by = blockIdx.y, n = blockIdx.z;
  const int y0 = by*2, x0 = bx*64;
  const int l = t & 63, w = t >> 6;
  const int lq = l & 15, kg = l >> 4;

  // staging: pure b128 copies (borders pre-zeroed; swizzle baked in global)
  const size_t gbase = (((size_t)n*PW + y0)*PW + x0)*64;
  for (int e = t; e < 4224; e += 256){
    const int plane = (e >= 2112);
    const int rem = e - plane*2112;
    const int row = rem / 528;
    const int cw = rem - row*528;
    const unsigned short* src = (plane ? inl : inh) + gbase + (size_t)row*(PW*64) + cw*8;
    *(uint4*)(cvsm + plane*33792 + row*8448 + cw*16) = *(const uint4*)src;
  }
  __syncthreads();

  constexpr int NCT = CO/16;
  f32x4 acc0[NCT], acc1[NCT];
  #pragma unroll
  for (int c=0;c<NCT;c++){ acc0[c] = (f32x4){0.f,0.f,0.f,0.f}; acc1[c] = acc0[c]; }
  const unsigned short* wlane = wsT + (size_t)lq*32 + (size_t)kg*8;

  #pragma unroll
  for (int tap=0; tap<9; ++tap){
    const int ky = tap/3, kx = tap - ky*3;
    const int col = w*16 + lq + kx;
    #pragma unroll
    for (int half=0; half<2; ++half){
      const int sci = ((((half<<2) | kg) ^ (col & 7)) << 3);
      FragU Bh0, Bl0, Bh1, Bl1;
      Bh0.i = *(const int4*)&inH[ky  ][col][sci];
      Bl0.i = *(const int4*)&inL[ky  ][col][sci];
      Bh1.i = *(const int4*)&inH[ky+1][col][sci];
      Bl1.i = *(const int4*)&inL[ky+1][col][sci];
      const unsigned short* wth = wlane + (size_t)((tap*2+half)*2)*CO*32;
      #pragma unroll
      for (int ct=0; ct<NCT; ++ct){
        FragU Ah, Al;
        Ah.i = *(const int4*)(wth + ct*512);
        Al.i = *(const int4*)(wth + CO*32 + ct*512);
        acc0[ct] = __builtin_amdgcn_mfma_f32_16x16x32_bf16(Ah.s, Bl0.s, acc0[ct], 0,0,0);
        acc0[ct] = __builtin_amdgcn_mfma_f32_16x16x32_bf16(Al.s, Bh0.s, acc0[ct], 0,0,0);
        acc0[ct] = __builtin_amdgcn_mfma_f32_16x16x32_bf16(Ah.s, Bh0.s, acc0[ct], 0,0,0);
        acc1[ct] = __builtin_amdgcn_mfma_f32_16x16x32_bf16(Ah.s, Bl1.s, acc1[ct], 0,0,0);
        acc1[ct] = __builtin_amdgcn_mfma_f32_16x16x32_bf16(Al.s, Bh1.s, acc1[ct], 0,0,0);
        acc1[ct] = __builtin_amdgcn_mfma_f32_16x16x32_bf16(Ah.s, Bh1.s, acc1[ct], 0,0,0);
      }
    }
  }

  const int px = x0 + w*16 + lq;
  const int xpad = px + 1;
  const int xg = xpad & 7;
  if constexpr (OMODE == 2){
    #pragma unroll
    for (int r=0; r<4; ++r){
      const int co = kg*4 + r;
      const float bv = bias[co];
      outf[((size_t)n*LL + (size_t)(y0  )*WW + px)*16 + co] = acc0[0][r] + bv;
      outf[((size_t)n*LL + (size_t)(y0+1)*WW + px)*16 + co] = acc1[0][r] + bv;
    }
  } else {
    #pragma unroll
    for (int ct=0; ct<NCT; ++ct){
      const int ci = ct*16 + kg*4;
      const int sgrp = (ct*2 + (kg>>1)) ^ xg;
      #pragma unroll
      for (int row=0; row<2; ++row){
        const f32x4& A = row ? acc1[ct] : acc0[ct];
        float v0 = fmaxf(A[0] + bias[ci+0], 0.f);
        float v1 = fmaxf(A[1] + bias[ci+1], 0.f);
        float v2 = fmaxf(A[2] + bias[ci+2], 0.f);
        float v3 = fmaxf(A[3] + bias[ci+3], 0.f);
        const unsigned int h0 = cvtpk_bf16(v0, v1);
        const unsigned int h1 = cvtpk_bf16(v2, v3);
        const unsigned int l0 = cvtpk_bf16(v0 - bfl(h0), v1 - bfh(h0));
        const unsigned int l1 = cvtpk_bf16(v2 - bfl(h1), v3 - bfh(h1));
        const size_t off = (((size_t)n*PW + (y0+row+1))*PW + xpad)*64 + sgrp*8 + (kg&1)*4;
        *(uint2*)(outh + off) = make_uint2(h0, h1);
        *(uint2*)(outl + off) = make_uint2(l0, l1);
        if constexpr (OMODE == 1){
          *(float4*)&outf[(((size_t)n*LL + (size_t)(y0+row)*WW + px)*64) + ci] =
              make_float4(v0, v1, v2, v3);
        }
      }
    }
  }
}

// ---------------- 1x1 conv (ye), x2 in fp32-NLC, out bf16 --------------------
__global__ __launch_bounds__(256) void k_conv1x1(const float* __restrict__ x2,
    const float* __restrict__ wa, const float* __restrict__ ba,
    unsigned short* __restrict__ yeB){
  __shared__ float xs[64][65];
  __shared__ float wts[64][65];
  const int t = threadIdx.x;
  const int n = blockIdx.y;
  const int l0 = blockIdx.x*64;
  for (int e=t; e<4096; e+=256){
    int lv = e >> 6, ci = e & 63;
    xs[ci][lv]  = x2[((size_t)n*LL + l0 + lv)*64 + ci];
    wts[ci][lv] = wa[(size_t)lv*64 + ci];
  }
  __syncthreads();
  const int l = t & 63, cq = t >> 6;
  float acc[16];
  #pragma unroll
  for (int i=0;i<16;i++) acc[i] = ba[cq*16+i];
  for (int ci=0; ci<64; ci++){
    float xv = xs[ci][l];
    #pragma unroll
    for (int i=0;i<16;i++) acc[i] = fmaf(xv, wts[ci][cq*16+i], acc[i]);
  }
  unsigned int wds[8];
  #pragma unroll
  for (int i=0;i<8;i++) wds[i] = cvtpk_bf16(acc[2*i], acc[2*i+1]);
  uint4* op = (uint4*)&yeB[((size_t)n*LL + l0 + l)*64 + cq*16];
  op[0] = make_uint4(wds[0],wds[1],wds[2],wds[3]);
  op[1] = make_uint4(wds[4],wds[5],wds[6],wds[7]);
}

// ---------------- LSH codes: argmax over [rot ; -rot] ------------------------
__global__ __launch_bounds__(128) void k_codes(const float* __restrict__ xe,
    const float* __restrict__ rot, unsigned char* __restrict__ codes){
  __shared__ float rs[NHASH][64][16];
  const int t = threadIdx.x;
  for (int e=t; e<4096; e+=128){
    int f = e >> 8; int rem = e & 255;
    int h = rem >> 6; int i = rem & 63;
    rs[h][i][f] = rot[((size_t)f*NHASH + h)*64 + i];
  }
  __syncthreads();
  const int n = blockIdx.y;
  const int l = blockIdx.x*128 + t;
  float q[16];
  const float* xr = &xe[((size_t)n*LL + l)*16];
  #pragma unroll
  for (int f=0;f<16;f++) q[f] = xr[f];
  #pragma unroll
  for (int h=0;h<NHASH;h++){
    float bp = -3.0e38f, bn = -3.0e38f; int ap=0, an=0;
    for (int i=0;i<64;i++){
      float s = 0.f;
      #pragma unroll
      for (int f=0;f<16;f++) s = fmaf(q[f], rs[h][i][f], s);
      if (s > bp){ bp = s; ap = i; }
      if (-s > bn){ bn = -s; an = i; }
    }
    int code = (bp >= bn) ? ap : (64 + an);
    codes[((size_t)n*NHASH + h)*LL + l] = (unsigned char)code;
  }
}

// ---------------- stable counting sort ---------------------------------------
__global__ __launch_bounds__(256) void k_hist(const unsigned char* __restrict__ codes,
    unsigned int* __restrict__ segHist){
  __shared__ unsigned int h[NBUCK];
  const int t = threadIdx.x;
  if (t < NBUCK) h[t] = 0;
  __syncthreads();
  const int n = blockIdx.z, hh = blockIdx.y, s = blockIdx.x;
  const unsigned char* cp = codes + ((size_t)n*NHASH + hh)*LL + (size_t)s*SEGL;
  for (int e=t; e<SEGL; e+=256) atomicAdd(&h[cp[e]], 1u);
  __syncthreads();
  if (t < NBUCK)
    segHist[(((size_t)(n*NHASH+hh))*NSEG + s)*NBUCK + t] = h[t];
}

__global__ __launch_bounds__(128) void k_scan(unsigned int* __restrict__ segHist){
  __shared__ unsigned int tot[NBUCK];
  __shared__ unsigned int base[NBUCK];
  const int b = threadIdx.x;
  const size_t off = (size_t)blockIdx.x * NSEG * NBUCK;
  unsigned int run = 0;
  for (int s=0;s<NSEG;s++){
    unsigned int v = segHist[off + (size_t)s*NBUCK + b];
    segHist[off + (size_t)s*NBUCK + b] = run;
    run += v;
  }
  tot[b] = run;
  __syncthreads();
  if (b==0){ unsigned int r=0; for (int i=0;i<NBUCK;i++){ base[i]=r; r+=tot[i]; } }
  __syncthreads();
  const unsigned int bb = base[b];
  for (int s=0;s<NSEG;s++) segHist[off + (size_t)s*NBUCK + b] += bb;
}

__global__ __launch_bounds__(256) void k_rank(const unsigned char* __restrict__ codes,
    const unsigned int* __restrict__ segHist, int* __restrict__ sortPos,
    int* __restrict__ srtIdx){
  __shared__ unsigned int cw[SEGL/4];
  __shared__ unsigned int sbase[NBUCK];
  const int t = threadIdx.x;
  const int n = blockIdx.z, hh = blockIdx.y, s = blockIdx.x;
  const size_t cb = ((size_t)n*NHASH + hh)*LL + (size_t)s*SEGL;
  const unsigned int* cp32 = (const unsigned int*)(codes + cb);
  for (int e=t; e<SEGL/4; e+=256) cw[e] = cp32[e];
  if (t < NBUCK)
    sbase[t] = segHist[(((size_t)(n*NHASH+hh))*NSEG + s)*NBUCK + t];
  __syncthreads();
  const size_t ob = ((size_t)n*NHASH + hh)*LL;
  for (int e=t; e<SEGL; e+=256){
    unsigned int c = (cw[e>>2] >> ((e&3)*8)) & 0xffu;
    unsigned int mul = c * 0x01010101u;
    int cnt = 0;
    const int nw = e >> 2;
    for (int wi=0; wi<nw; wi++){
      unsigned int v = cw[wi] ^ mul;
      unsigned int t1 = (v & 0x7f7f7f7fu) + 0x7f7f7f7fu;
      unsigned int z = ~(t1 | v) & 0x80808080u;
      cnt += __popc(z);
    }
    unsigned int lastw = cw[nw];
    const int nbp = e & 3;
    for (int bp=0; bp<nbp; bp++)
      if (((lastw >> (bp*8)) & 0xffu) == c) cnt++;
    int pos = (int)sbase[c] + cnt;
    int lx = s*SEGL + e;
    sortPos[ob + lx] = pos;
    srtIdx[ob + pos] = lx;
  }
}

// ---------------- pre-gather K -----------------------------------------------
__global__ __launch_bounds__(256) void k_gatherK(const float* __restrict__ xe,
    const int* __restrict__ srtIdx, unsigned short* __restrict__ Ksrt,
    float* __restrict__ normQ){
  const int idx = blockIdx.x*256 + threadIdx.x;
  if (idx >= NB*NHASH*LL) return;
  const int n = idx / (NHASH*LL);
  const int lk = srtIdx[idx];
  const float4* xr = (const float4*)&xe[((size_t)n*LL + lk)*16];
  float4 v0 = xr[0], v1 = xr[1], v2 = xr[2], v3 = xr[3];
  float f[16] = {v0.x,v0.y,v0.z,v0.w, v1.x,v1.y,v1.z,v1.w,
                 v2.x,v2.y,v2.z,v2.w, v3.x,v3.y,v3.z,v3.w};
  float ss = 0.f;
  #pragma unroll
  for (int i=0;i<16;i++) ss = fmaf(f[i], f[i], ss);
  const float nq = sqrtf(ss);
  normQ[idx] = nq;
  const float inv = 1.f / fmaxf(nq, 5e-5f);
  #pragma unroll
  for (int i=0;i<16;i++) f[i] *= inv;
  unsigned int kh[8], klo[8];
  #pragma unroll
  for (int i=0;i<8;i++) kh[i] = cvtpk_bf16(f[2*i], f[2*i+1]);
  #pragma unroll
  for (int i=0;i<8;i++)
    klo[i] = cvtpk_bf16(f[2*i] - bfl(kh[i]), f[2*i+1] - bfh(kh[i]));
  int4* kr = (int4*)(Ksrt + (size_t)idx*32);
  kr[0] = make_int4((int)kh[0],(int)kh[1],(int)kh[2],(int)kh[3]);
  kr[1] = make_int4((int)kh[4],(int)kh[5],(int)kh[6],(int)kh[7]);
  kr[2] = make_int4((int)klo[0],(int)klo[1],(int)klo[2],(int)klo[3]);
  kr[3] = make_int4((int)klo[4],(int)klo[5],(int)klo[6],(int)klo[7]);
}

// ---------------- attention (R5-exact tier-1) --------------------------------
__global__ __launch_bounds__(576) void k_attn2(const unsigned short* __restrict__ yeB,
    const int* __restrict__ srtIdx, const unsigned short* __restrict__ Ksrt,
    const float* __restrict__ normQ, unsigned short* __restrict__ retS,
    float* __restrict__ bscore){
  extern __shared__ char smem[];
  char* Vt  = smem;
  char* Pst = Vt + VT_SZB;
  int* lkI  = (int*)(Pst + PST_SZB);

  const int t = threadIdx.x;
  const int k = blockIdx.x, hh = blockIdx.y, n = blockIdx.z;
  const size_t sb = ((size_t)n*NHASH + hh)*LL;
  const int l = t & 63, w = t >> 6;
  const int lq16 = l & 15, g = l >> 4;

  if (t < 432){
    const int c3 = t / CHK, jl = t - c3*CHK;
    const int kc = (c3==0) ? k : ((c3==1) ? ((k+NCHK-1)&(NCHK-1)) : ((k+1)&(NCHK-1)));
    lkI[t] = srtIdx[sb + (size_t)kc*CHK + jl];
  }
  if (t < 512){
    int c = t >> 3, jp = t & 7;
    *(unsigned int*)(Vt + c*V_ROWB + 864 + jp*4) = 0u;
  }
  __syncthreads();

  #pragma unroll 4
  for (int it=0; it<24; ++it){
    const int e = t + it*576;
    const int jp = e >> 6, c = e & 63;
    const unsigned int a = yeB[((size_t)n*LL + lkI[2*jp  ])*64 + c];
    const unsigned int b = yeB[((size_t)n*LL + lkI[2*jp+1])*64 + c];
    *(unsigned int*)(Vt + c*V_ROWB + jp*4) = a | (b << 16);
  }
  const int qg = w*16 + lq16;
  const int pq = k*CHK + qg;
  FragU b1, b2;
  const unsigned short* qrow = Ksrt + (sb + pq)*32;
  b1.i = *(const int4*)(qrow + (g&1)*8);
  if (g < 2) b2.i = *(const int4*)(qrow + 16 + (g&1)*8);
  else { b2.u[0]=0u; b2.u[1]=0u; b2.u[2]=0u; b2.u[3]=0u; }
  const float nq_ = normQ[sb + pq];
  const float msc = fmaxf(nq_, 5e-5f);
  __syncthreads();

  float sum = 0.f;
  f32x4 O0 = {0.f,0.f,0.f,0.f}, O1 = O0, O2 = O0, O3 = O0;
  char* Pw = Pst + w*(16*P_ROWB);
  for (int u=0; u<14; ++u){
    #pragma unroll
    for (int sub=0; sub<2; ++sub){
      const int t27 = u*2 + sub;
      uint2 pw;
      if (t27 < 27){
        const int c3 = t27 / 9;
        const int kc = (c3==0) ? k : ((c3==1) ? ((k+NCHK-1)&(NCHK-1)) : ((k+1)&(NCHK-1)));
        const int row16 = (t27 - c3*9)*16;
        FragU a; a.i = *(const int4*)(Ksrt + (sb + (size_t)kc*CHK + row16 + lq16)*32 + g*8);
        f32x4 C = {0.f,0.f,0.f,0.f};
        C = __builtin_amdgcn_mfma_f32_16x16x32_bf16(a.s, b2.s, C, 0, 0, 0);
        C = __builtin_amdgcn_mfma_f32_16x16x32_bf16(a.s, b1.s, C, 0, 0, 0);
        const float p0 = __expf(fmaf(msc, C[0], -nq_));
        const float p1 = __expf(fmaf(msc, C[1], -nq_));
        const float p2 = __expf(fmaf(msc, C[2], -nq_));
        const float p3 = __expf(fmaf(msc, C[3], -nq_));
        sum += (p0+p1) + (p2+p3);
        pw = make_uint2(cvtpk_bf16(p0,p1), cvtpk_bf16(p2,p3));
      } else {
        pw = make_uint2(0u, 0u);
      }
      *(uint2*)(Pw + lq16*P_ROWB + sub*32 + g*8) = pw;
    }
    asm volatile("s_waitcnt lgkmcnt(0)" ::: "memory");
    __builtin_amdgcn_sched_barrier(0);
    FragU bp; bp.i = *(const int4*)(Pw + lq16*P_ROWB + g*16);
    const char* Vb = Vt + lq16*V_ROWB + u*64 + g*16;
    FragU av;
    av.i = *(const int4*)(Vb);             O0 = __builtin_amdgcn_mfma_f32_16x16x32_bf16(av.s, bp.s, O0, 0,0,0);
    av.i = *(const int4*)(Vb + 16*V_ROWB); O1 = __builtin_amdgcn_mfma_f32_16x16x32_bf16(av.s, bp.s, O1, 0,0,0);
    av.i = *(const int4*)(Vb + 32*V_ROWB); O2 = __builtin_amdgcn_mfma_f32_16x16x32_bf16(av.s, bp.s, O2, 0,0,0);
    av.i = *(const int4*)(Vb + 48*V_ROWB); O3 = __builtin_amdgcn_mfma_f32_16x16x32_bf16(av.s, bp.s, O3, 0,0,0);
  }
  sum += __shfl_xor(sum, 16);
  sum += __shfl_xor(sum, 32);
  const float linv = 1.f / sum;

  unsigned short* op = &retS[(sb + pq)*64];
  {
    uint2 s0 = make_uint2(cvtpk_bf16(O0[0]*linv, O0[1]*linv), cvtpk_bf16(O0[2]*linv, O0[3]*linv));
    uint2 s1 = make_uint2(cvtpk_bf16(O1[0]*linv, O1[1]*linv), cvtpk_bf16(O1[2]*linv, O1[3]*linv));
    uint2 s2 = make_uint2(cvtpk_bf16(O2[0]*linv, O2[1]*linv), cvtpk_bf16(O2[2]*linv, O2[3]*linv));
    uint2 s3 = make_uint2(cvtpk_bf16(O3[0]*linv, O3[1]*linv), cvtpk_bf16(O3[2]*linv, O3[3]*linv));
    *(uint2*)(op +  0 + g*4) = s0;
    *(uint2*)(op + 16 + g*4) = s1;
    *(uint2*)(op + 32 + g*4) = s2;
    *(uint2*)(op + 48 + g*4) = s3;
  }
  if (g == 0) bscore[sb + pq] = nq_ + logf(sum);
}

// ---------------- unsort + hash-softmax combine + residual -------------------
__global__ __launch_bounds__(256) void k_combine(const unsigned short* __restrict__ retS,
    const float* __restrict__ bscore, const int* __restrict__ sortPos,
    const float* __restrict__ x2, float* __restrict__ out){
  const int idx = blockIdx.x*256 + threadIdx.x;
  if (idx >= NB*LL) return;
  const int l = idx % LL, n = idx / LL;
  float bs[NHASH]; int pp[NHASH];
  #pragma unroll
  for (int h=0;h<NHASH;h++){
    size_t sb = ((size_t)n*NHASH + h)*LL;
    int p = sortPos[sb + l];
    pp[h] = p; bs[h] = bscore[sb + p];
  }
  float m = fmaxf(fmaxf(bs[0],bs[1]), fmaxf(bs[2],bs[3]));
  float wsum = 0.f; float wv[NHASH];
  #pragma unroll
  for (int h=0;h<NHASH;h++){ wv[h] = expf(bs[h]-m); wsum += wv[h]; }
  const float winv = 1.f / wsum;
  float o[64];
  #pragma unroll
  for (int i=0;i<64;i++) o[i]=0.f;
  #pragma unroll
  for (int h=0;h<NHASH;h++){
    const float wh = wv[h]*winv;
    const uint4* rp = (const uint4*)&retS[(((size_t)n*NHASH + h)*LL + pp[h])*64];
    #pragma unroll
    for (int i2=0;i2<8;i2++){
      uint4 v = rp[i2];
      o[i2*8+0] = fmaf(wh, bfl(v.x), o[i2*8+0]);
      o[i2*8+1] = fmaf(wh, bfh(v.x), o[i2*8+1]);
      o[i2*8+2] = fmaf(wh, bfl(v.y), o[i2*8+2]);
      o[i2*8+3] = fmaf(wh, bfh(v.y), o[i2*8+3]);
      o[i2*8+4] = fmaf(wh, bfl(v.z), o[i2*8+4]);
      o[i2*8+5] = fmaf(wh, bfh(v.z), o[i2*8+5]);
      o[i2*8+6] = fmaf(wh, bfl(v.w), o[i2*8+6]);
      o[i2*8+7] = fmaf(wh, bfh(v.w), o[i2*8+7]);
    }
  }
  const float4* xr = (const float4*)&x2[((size_t)n*LL + l)*64];
  #pragma unroll
  for (int c4=0; c4<16; ++c4){
    float4 xv = xr[c4];
    out[((size_t)n*64 + c4*4+0)*LL + l] = o[c4*4+0] + xv.x;
    out[((size_t)n*64 + c4*4+1)*LL + l] = o[c4*4+1] + xv.y;
    out[((size_t)n*64 + c4*4+2)*LL + l] = o[c4*4+2] + xv.z;
    out[((size_t)n*64 + c4*4+3)*LL + l] = o[c4*4+3] + xv.w;
  }
}

extern "C" void kernel_launch(void* const* d_in, const int* in_sizes, int n_in,
                              void* d_out, int out_size, void* d_ws, size_t ws_size,
                              hipStream_t stream){
  const float* x   = (const float*)d_in[0];
  const float* w1  = (const float*)d_in[1];
  const float* b1  = (const float*)d_in[2];
  const float* w2  = (const float*)d_in[3];
  const float* b2  = (const float*)d_in[4];
  const float* wm  = (const float*)d_in[5];
  const float* bm  = (const float*)d_in[6];
  const float* wa  = (const float*)d_in[7];
  const float* ba  = (const float*)d_in[8];
  const float* rot = (const float*)d_in[9];
  float* outp = (float*)d_out;
  char* ws = (char*)d_ws;
  const size_t FM   = (size_t)NB*CIN*HH*WW*sizeof(float);
  const size_t YEB  = (size_t)NB*LL*64*2;
  const size_t RETB = (size_t)NB*NHASH*LL*64*2;
  const size_t NHL4 = (size_t)NB*NHASH*LL*4;

  char* p = ws;
  unsigned short* yeB = (unsigned short*)p;  p += YEB;
  char* regA = p;                            p += RETB;   // retS | pairA (xh0/xl0, xh2/xl2)
  float* x2  = (float*)p;                    p += FM;     // fp32 NLC64
  float* xe  = (float*)p;                    p += (size_t)NB*LL*CE*sizeof(float);
  unsigned char* codes = (unsigned char*)p;  p += (size_t)NB*NHASH*LL;
  unsigned int* segHist = (unsigned int*)p;  p += (size_t)NB*NHASH*NSEG*NBUCK*4;
  int* sortPos = (int*)p;                    p += NHL4;
  int* srtIdx  = (int*)p;                    p += NHL4;
  float* bscore = (float*)p;                 p += NHL4;
  unsigned short* wsT1 = (unsigned short*)p; p += (size_t)9*2*2*64*32*2;
  unsigned short* wsT2 = (unsigned short*)p; p += (size_t)9*2*2*64*32*2;
  unsigned short* wsTm = (unsigned short*)p; p += (size_t)9*2*2*16*32*2;
  unsigned short* Ksrt = (unsigned short*)p; p += (size_t)NB*NHASH*LL*32*2;  // | pairB
  float* normQ = (float*)p;                  p += NHL4;
  const size_t needT1 = (size_t)(p - ws);
  if (ws_size < needT1) return;

  unsigned short* retS = (unsigned short*)regA;
  unsigned short* pairA = (unsigned short*)regA;          // xh at +0, xl at +PS
  unsigned short* pairB = Ksrt;                           // spans Ksrt+normQ (fits)

  hipFuncSetAttribute((const void*)k_attn2,
                      hipFuncAttributeMaxDynamicSharedMemorySize, LDS_T1);
  hipFuncSetAttribute((const void*)k_conv3s<64,0>,
                      hipFuncAttributeMaxDynamicSharedMemorySize, CONV_LDS);
  hipFuncSetAttribute((const void*)k_conv3s<64,1>,
                      hipFuncAttributeMaxDynamicSharedMemorySize, CONV_LDS);
  hipFuncSetAttribute((const void*)k_conv3s<16,2>,
                      hipFuncAttributeMaxDynamicSharedMemorySize, CONV_LDS);

  k_prepw<<<dim3((64*64*9+255)/256), dim3(256), 0, stream>>>(w1, wsT1, 64);
  k_prepw<<<dim3((64*64*9+255)/256), dim3(256), 0, stream>>>(w2, wsT2, 64);
  k_prepw<<<dim3((16*64*9+255)/256), dim3(256), 0, stream>>>(wm, wsTm, 16);
  k_zerob<<<dim3((4*2*772*8+255)/256), dim3(256), 0, stream>>>(pairA, pairB);
  // upsample -> pairA (split padded NLC)
  k_upsample2<<<dim3(WW/64, HH, NB), dim3(256), 0, stream>>>(x, pairA, pairA + PS);
  // conv1: pairA -> pairB
  k_conv3s<64,0><<<dim3(3, HH/2, NB), dim3(256), CONV_LDS, stream>>>(
      pairA, pairA + PS, wsT1, b1, pairB, pairB + PS, nullptr);
  // conv2: pairB -> pairA (xh2) + x2 fp32 NLC
  k_conv3s<64,1><<<dim3(3, HH/2, NB), dim3(256), CONV_LDS, stream>>>(
      pairB, pairB + PS, wsT2, b2, pairA, pairA + PS, x2);
  // wm conv: pairA -> xe (fp32 NLC16)
  k_conv3s<16,2><<<dim3(3, HH/2, NB), dim3(256), CONV_LDS, stream>>>(
      pairA, pairA + PS, wsTm, bm, nullptr, nullptr, xe);
  k_conv1x1<<<dim3(LL/64, NB), dim3(256), 0, stream>>>(x2, wa, ba, yeB);
  k_codes<<<dim3(LL/128, NB), dim3(128), 0, stream>>>(xe, rot, codes);
  k_hist<<<dim3(NSEG, NHASH, NB), dim3(256), 0, stream>>>(codes, segHist);
  k_scan<<<dim3(NB*NHASH), dim3(128), 0, stream>>>(segHist);
  k_rank<<<dim3(NSEG, NHASH, NB), dim3(256), 0, stream>>>(codes, segHist, sortPos, srtIdx);
  k_gatherK<<<dim3((NB*NHASH*LL+255)/256), dim3(256), 0, stream>>>(xe, srtIdx, Ksrt, normQ);
  k_attn2<<<dim3(NCHK, NHASH, NB), dim3(576), LDS_T1, stream>>>(
      yeB, srtIdx, Ksrt, normQ, retS, bscore);
  k_combine<<<dim3((NB*LL+255)/256), dim3(256), 0, stream>>>(retS, bscore, sortPos, x2, outp);
}

// Round 14
// 341.266 us; speedup vs baseline: 1.4395x; 1.0231x over previous
//
#include <hip/hip_runtime.h>
#include <math.h>

#define NB 2
#define CIN 64
#define H0 96
#define W0 96
#define HH 192
#define WW 192
#define LL (HH*WW)        // 36864
#define NHASH 4
#define CHK 144
#define NCHK 256          // LL/CHK
#define CE 16
#define NBUCK 128
#define SEGL 576
#define NSEG 64           // LL/SEGL
#define PW 194            // padded width/height
#define PS ((size_t)NB*PW*PW*64)   // shorts per split plane

// ---- attention LDS layout (bytes) ----
#define K_ROWB   80
#define V_ROWB   912
#define P_ROWB   80              // was 72: 16B-aligned rows, 5-slot cycle (odd*16)
#define VT_SZB   58368
#define PST_SZB  11520           // 9 waves * 16 * 80
#define LKI_SZB  1728
#define LDS_T1   (VT_SZB + PST_SZB + LKI_SZB)   // 71616 (<= 80KB, 2 blocks/CU)
#define CONV_LDS (2*4*66*64*2)                  // 67584

typedef __attribute__((ext_vector_type(8))) short short8_t;
typedef __attribute__((ext_vector_type(4))) float f32x4;
union FragU { unsigned int u[4]; int4 i; short8_t s; };

__device__ __forceinline__ unsigned int cvtpk_bf16(float a, float b){
  unsigned int r;
  asm("v_cvt_pk_bf16_f32 %0, %1, %2" : "=v"(r) : "v"(a), "v"(b));
  return r;
}
__device__ __forceinline__ float bfl(unsigned int u){ return __uint_as_float(u << 16); }
__device__ __forceinline__ float bfh(unsigned int u){ return __uint_as_float(u & 0xffff0000u); }

// ---------------- zero borders of the 4 split planes -------------------------
__global__ __launch_bounds__(256) void k_zerob(unsigned short* pA, unsigned short* pB){
  const int cid = blockIdx.x*256 + threadIdx.x;
  if (cid >= 4*2*772*8) return;
  const int chunk = cid & 7;
  int cell = cid >> 3;
  const int plane = cell / (2*772); cell -= plane*(2*772);
  const int n = cell / 772; int b = cell - n*772;
  int ypad, xpad;
  if (b < 194){ ypad = 0; xpad = b; }
  else if (b < 388){ ypad = 193; xpad = b-194; }
  else if (b < 580){ ypad = b-388+1; xpad = 0; }
  else { ypad = b-580+1; xpad = 193; }
  unsigned short* base = (plane < 2 ? pA : pB) + (size_t)(plane & 1)*PS;
  *(uint4*)(base + (((size_t)n*PW + ypad)*PW + xpad)*64 + chunk*8) =
      make_uint4(0u,0u,0u,0u);
}

// ---------------- bicubic 2x upsample -> split padded NLC --------------------
__global__ __launch_bounds__(256) void k_upsample2(const float* __restrict__ x,
    unsigned short* __restrict__ oh, unsigned short* __restrict__ ol){
  __shared__ unsigned int pk[64][65];
  const int t = threadIdx.x;
  const int bx = blockIdx.x, oy = blockIdx.y, n = blockIdx.z;
  const int oxl = t & 63, cq = t >> 6;
  const int ox = bx*64 + oxl;
  const int i = oy >> 1, a = oy & 1;
  const int j = ox >> 1, b = ox & 1;
  const float e0=-0.03515625f, e1=0.26171875f, e2=0.87890625f, e3=-0.10546875f;
  float wy[4], wx[4]; int ty[4], tx[4];
  if (a){ wy[0]=e3; wy[1]=e2; wy[2]=e1; wy[3]=e0; } else { wy[0]=e0; wy[1]=e1; wy[2]=e2; wy[3]=e3; }
  if (b){ wx[0]=e3; wx[1]=e2; wx[2]=e1; wx[3]=e0; } else { wx[0]=e0; wx[1]=e1; wx[2]=e2; wx[3]=e3; }
  const int offy = a ? -1 : -2, offx = b ? -1 : -2;
  #pragma unroll
  for (int k=0;k<4;k++){
    int u = i + offy + k; ty[k] = u<0?0:(u>H0-1?H0-1:u);
    int s = j + offx + k; tx[k] = s<0?0:(s>W0-1?W0-1:s);
  }
  for (int ci = cq*16; ci < cq*16+16; ++ci){
    const float* xp = x + ((size_t)n*CIN + ci)*(H0*W0);
    float s = 0.f;
    #pragma unroll
    for (int ky=0;ky<4;ky++){
      const float* row = xp + ty[ky]*W0;
      float rs = 0.f;
      rs = fmaf(wx[0], row[tx[0]], rs);
      rs = fmaf(wx[1], row[tx[1]], rs);
      rs = fmaf(wx[2], row[tx[2]], rs);
      rs = fmaf(wx[3], row[tx[3]], rs);
      s = fmaf(wy[ky], rs, s);
    }
    unsigned int hu = cvtpk_bf16(s, s);
    unsigned int lu = cvtpk_bf16(s - bfl(hu), 0.f);
    pk[oxl][ci] = (hu & 0xffffu) | (lu << 16);
  }
  __syncthreads();
  const size_t rowb = (((size_t)n*PW + oy+1)*PW + bx*64 + 1)*64;
  for (int e = t; e < 1024; e += 256){
    const int plane = e >> 9, r2 = e & 511;
    const int ox2 = r2 >> 3, c8 = r2 & 7;
    const int xpad = bx*64 + ox2 + 1;
    const int grp = (c8 ^ (xpad & 7))*8;
    unsigned int a0=pk[ox2][grp+0], a1=pk[ox2][grp+1], a2=pk[ox2][grp+2], a3=pk[ox2][grp+3];
    unsigned int a4=pk[ox2][grp+4], a5=pk[ox2][grp+5], a6=pk[ox2][grp+6], a7=pk[ox2][grp+7];
    uint4 wv;
    if (plane == 0){
      wv.x = (a0&0xffffu)|(a1<<16); wv.y = (a2&0xffffu)|(a3<<16);
      wv.z = (a4&0xffffu)|(a5<<16); wv.w = (a6&0xffffu)|(a7<<16);
    } else {
      wv.x = (a0>>16)|(a1&0xffff0000u); wv.y = (a2>>16)|(a3&0xffff0000u);
      wv.z = (a4>>16)|(a5&0xffff0000u); wv.w = (a6>>16)|(a7&0xffff0000u);
    }
    *(uint4*)((plane ? ol : oh) + rowb + (size_t)ox2*64 + c8*8) = wv;
  }
}

// ---------------- weight prep: fp32 OIHW -> bf16x2 frag layout ---------------
__global__ __launch_bounds__(256) void k_prepw(const float* __restrict__ w,
    unsigned short* __restrict__ wsT, int CO){
  int idx = blockIdx.x*256 + threadIdx.x;
  if (idx >= CO*64*9) return;
  int tap = idx % 9; int rem = idx / 9;
  int ci = rem % 64; int co = rem / 64;
  float v = w[(size_t)(co*64 + ci)*9 + tap];
  unsigned int hu = cvtpk_bf16(v, v) & 0xffffu;
  float hf = bfl(hu);
  unsigned int lu = cvtpk_bf16(v - hf, 0.f) & 0xffffu;
  int half = ci >> 5, kg = (ci >> 3) & 3, e = ci & 7;
  size_t base = ((size_t)(tap*2 + half)*2)*CO*32 + ((size_t)co*4 + kg)*8 + e;
  wsT[base]         = (unsigned short)hu;
  wsT[base + (size_t)CO*32] = (unsigned short)lu;
}

// ---------------- 3x3 conv via MFMA, bf16x3; pre-split padded-NLC input ------
// OMODE 0: split-NLC out (+relu); 1: split-NLC + fp32-NLC64 out (+relu);
// OMODE 2: fp32-NLC16 out (no relu).
template<int CO, int OMODE>
__global__ __launch_bounds__(256) void k_conv3s(const unsigned short* __restrict__ inh,
    const unsigned short* __restrict__ inl, const unsigned short* __restrict__ wsT,
    const float* __restrict__ bias, unsigned short* __restrict__ outh,
    unsigned short* __restrict__ outl, float* __restrict__ outf){
  extern __shared__ char cvsm[];
  unsigned short (*inH)[66][64] = (unsigned short (*)[66][64])cvsm;
  unsigned short (*inL)[66][64] = (unsigned short (*)[66][64])(cvsm + 33792);
  const int t = threadIdx.x;
  const int bx = blockIdx.x, by = blockIdx.y, n = blockIdx.z;
  const int y0 = by*2, x0 = bx*64;
  const int l = t & 63, w = t >> 6;
  const int lq = l & 15, kg = l >> 4;

  // staging: pure b128 copies (borders pre-zeroed; swizzle baked in global)
  const size_t gbase = (((size_t)n*PW + y0)*PW + x0)*64;
  for (int e = t; e < 4224; e += 256){
    const int plane = (e >= 2112);
    const int rem = e - plane*2112;
    const int row = rem / 528;
    const int cw = rem - row*528;
    const unsigned short* src = (plane ? inl : inh) + gbase + (size_t)row*(PW*64) + cw*8;
    *(uint4*)(cvsm + plane*33792 + row*8448 + cw*16) = *(const uint4*)src;
  }
  __syncthreads();

  constexpr int NCT = CO/16;
  f32x4 acc0[NCT], acc1[NCT];
  #pragma unroll
  for (int c=0;c<NCT;c++){ acc0[c] = (f32x4){0.f,0.f,0.f,0.f}; acc1[c] = acc0[c]; }
  const unsigned short* wlane = wsT + (size_t)lq*32 + (size_t)kg*8;

  #pragma unroll
  for (int tap=0; tap<9; ++tap){
    const int ky = tap/3, kx = tap - ky*3;
    const int col = w*16 + lq + kx;
    #pragma unroll
    for (int half=0; half<2; ++half){
      const int sci = ((((half<<2) | kg) ^ (col & 7)) << 3);
      FragU Bh0, Bl0, Bh1, Bl1;
      Bh0.i = *(const int4*)&inH[ky  ][col][sci];
      Bl0.i = *(const int4*)&inL[ky  ][col][sci];
      Bh1.i = *(const int4*)&inH[ky+1][col][sci];
      Bl1.i = *(const int4*)&inL[ky+1][col][sci];
      const unsigned short* wth = wlane + (size_t)((tap*2+half)*2)*CO*32;
      #pragma unroll
      for (int ct=0; ct<NCT; ++ct){
        FragU Ah, Al;
        Ah.i = *(const int4*)(wth + ct*512);
        Al.i = *(const int4*)(wth + CO*32 + ct*512);
        acc0[ct] = __builtin_amdgcn_mfma_f32_16x16x32_bf16(Ah.s, Bl0.s, acc0[ct], 0,0,0);
        acc0[ct] = __builtin_amdgcn_mfma_f32_16x16x32_bf16(Al.s, Bh0.s, acc0[ct], 0,0,0);
        acc0[ct] = __builtin_amdgcn_mfma_f32_16x16x32_bf16(Ah.s, Bh0.s, acc0[ct], 0,0,0);
        acc1[ct] = __builtin_amdgcn_mfma_f32_16x16x32_bf16(Ah.s, Bl1.s, acc1[ct], 0,0,0);
        acc1[ct] = __builtin_amdgcn_mfma_f32_16x16x32_bf16(Al.s, Bh1.s, acc1[ct], 0,0,0);
        acc1[ct] = __builtin_amdgcn_mfma_f32_16x16x32_bf16(Ah.s, Bh1.s, acc1[ct], 0,0,0);
      }
    }
  }

  const int px = x0 + w*16 + lq;
  const int xpad = px + 1;
  const int xg = xpad & 7;
  if constexpr (OMODE == 2){
    #pragma unroll
    for (int r=0; r<4; ++r){
      const int co = kg*4 + r;
      const float bv = bias[co];
      outf[((size_t)n*LL + (size_t)(y0  )*WW + px)*16 + co] = acc0[0][r] + bv;
      outf[((size_t)n*LL + (size_t)(y0+1)*WW + px)*16 + co] = acc1[0][r] + bv;
    }
  } else {
    #pragma unroll
    for (int ct=0; ct<NCT; ++ct){
      const int ci = ct*16 + kg*4;
      const int sgrp = (ct*2 + (kg>>1)) ^ xg;
      #pragma unroll
      for (int row=0; row<2; ++row){
        const f32x4& A = row ? acc1[ct] : acc0[ct];
        float v0 = fmaxf(A[0] + bias[ci+0], 0.f);
        float v1 = fmaxf(A[1] + bias[ci+1], 0.f);
        float v2 = fmaxf(A[2] + bias[ci+2], 0.f);
        float v3 = fmaxf(A[3] + bias[ci+3], 0.f);
        const unsigned int h0 = cvtpk_bf16(v0, v1);
        const unsigned int h1 = cvtpk_bf16(v2, v3);
        const unsigned int l0 = cvtpk_bf16(v0 - bfl(h0), v1 - bfh(h0));
        const unsigned int l1 = cvtpk_bf16(v2 - bfl(h1), v3 - bfh(h1));
        const size_t off = (((size_t)n*PW + (y0+row+1))*PW + xpad)*64 + sgrp*8 + (kg&1)*4;
        *(uint2*)(outh + off) = make_uint2(h0, h1);
        *(uint2*)(outl + off) = make_uint2(l0, l1);
        if constexpr (OMODE == 1){
          *(float4*)&outf[(((size_t)n*LL + (size_t)(y0+row)*WW + px)*64) + ci] =
              make_float4(v0, v1, v2, v3);
        }
      }
    }
  }
}

// ---------------- 1x1 conv (ye), x2 in fp32-NLC, out bf16 --------------------
__global__ __launch_bounds__(256) void k_conv1x1(const float* __restrict__ x2,
    const float* __restrict__ wa, const float* __restrict__ ba,
    unsigned short* __restrict__ yeB){
  __shared__ float xs[64][65];
  __shared__ float wts[64][65];
  const int t = threadIdx.x;
  const int n = blockIdx.y;
  const int l0 = blockIdx.x*64;
  for (int e=t; e<4096; e+=256){
    int lv = e >> 6, ci = e & 63;
    xs[ci][lv]  = x2[((size_t)n*LL + l0 + lv)*64 + ci];
    wts[ci][lv] = wa[(size_t)lv*64 + ci];
  }
  __syncthreads();
  const int l = t & 63, cq = t >> 6;
  float acc[16];
  #pragma unroll
  for (int i=0;i<16;i++) acc[i] = ba[cq*16+i];
  for (int ci=0; ci<64; ci++){
    float xv = xs[ci][l];
    #pragma unroll
    for (int i=0;i<16;i++) acc[i] = fmaf(xv, wts[ci][cq*16+i], acc[i]);
  }
  unsigned int wds[8];
  #pragma unroll
  for (int i=0;i<8;i++) wds[i] = cvtpk_bf16(acc[2*i], acc[2*i+1]);
  uint4* op = (uint4*)&yeB[((size_t)n*LL + l0 + l)*64 + cq*16];
  op[0] = make_uint4(wds[0],wds[1],wds[2],wds[3]);
  op[1] = make_uint4(wds[4],wds[5],wds[6],wds[7]);
}

// ---------------- LSH codes: argmax over [rot ; -rot] ------------------------
__global__ __launch_bounds__(128) void k_codes(const float* __restrict__ xe,
    const float* __restrict__ rot, unsigned char* __restrict__ codes){
  __shared__ float rs[NHASH][64][16];
  const int t = threadIdx.x;
  for (int e=t; e<4096; e+=128){
    int f = e >> 8; int rem = e & 255;
    int h = rem >> 6; int i = rem & 63;
    rs[h][i][f] = rot[((size_t)f*NHASH + h)*64 + i];
  }
  __syncthreads();
  const int n = blockIdx.y;
  const int l = blockIdx.x*128 + t;
  float q[16];
  const float* xr = &xe[((size_t)n*LL + l)*16];
  #pragma unroll
  for (int f=0;f<16;f++) q[f] = xr[f];
  #pragma unroll
  for (int h=0;h<NHASH;h++){
    float bp = -3.0e38f, bn = -3.0e38f; int ap=0, an=0;
    for (int i=0;i<64;i++){
      float s = 0.f;
      #pragma unroll
      for (int f=0;f<16;f++) s = fmaf(q[f], rs[h][i][f], s);
      if (s > bp){ bp = s; ap = i; }
      if (-s > bn){ bn = -s; an = i; }
    }
    int code = (bp >= bn) ? ap : (64 + an);
    codes[((size_t)n*NHASH + h)*LL + l] = (unsigned char)code;
  }
}

// ---------------- stable counting sort ---------------------------------------
__global__ __launch_bounds__(256) void k_hist(const unsigned char* __restrict__ codes,
    unsigned int* __restrict__ segHist){
  __shared__ unsigned int h[NBUCK];
  const int t = threadIdx.x;
  if (t < NBUCK) h[t] = 0;
  __syncthreads();
  const int n = blockIdx.z, hh = blockIdx.y, s = blockIdx.x;
  const unsigned char* cp = codes + ((size_t)n*NHASH + hh)*LL + (size_t)s*SEGL;
  for (int e=t; e<SEGL; e+=256) atomicAdd(&h[cp[e]], 1u);
  __syncthreads();
  if (t < NBUCK)
    segHist[(((size_t)(n*NHASH+hh))*NSEG + s)*NBUCK + t] = h[t];
}

__global__ __launch_bounds__(128) void k_scan(unsigned int* __restrict__ segHist){
  __shared__ unsigned int tot[NBUCK];
  __shared__ unsigned int base[NBUCK];
  const int b = threadIdx.x;
  const size_t off = (size_t)blockIdx.x * NSEG * NBUCK;
  unsigned int run = 0;
  for (int s=0;s<NSEG;s++){
    unsigned int v = segHist[off + (size_t)s*NBUCK + b];
    segHist[off + (size_t)s*NBUCK + b] = run;
    run += v;
  }
  tot[b] = run;
  __syncthreads();
  if (b==0){ unsigned int r=0; for (int i=0;i<NBUCK;i++){ base[i]=r; r+=tot[i]; } }
  __syncthreads();
  const unsigned int bb = base[b];
  for (int s=0;s<NSEG;s++) segHist[off + (size_t)s*NBUCK + b] += bb;
}

__global__ __launch_bounds__(256) void k_rank(const unsigned char* __restrict__ codes,
    const unsigned int* __restrict__ segHist, int* __restrict__ sortPos,
    int* __restrict__ srtIdx){
  __shared__ unsigned int cw[SEGL/4];
  __shared__ unsigned int sbase[NBUCK];
  const int t = threadIdx.x;
  const int n = blockIdx.z, hh = blockIdx.y, s = blockIdx.x;
  const size_t cb = ((size_t)n*NHASH + hh)*LL + (size_t)s*SEGL;
  const unsigned int* cp32 = (const unsigned int*)(codes + cb);
  for (int e=t; e<SEGL/4; e+=256) cw[e] = cp32[e];
  if (t < NBUCK)
    sbase[t] = segHist[(((size_t)(n*NHASH+hh))*NSEG + s)*NBUCK + t];
  __syncthreads();
  const size_t ob = ((size_t)n*NHASH + hh)*LL;
  for (int e=t; e<SEGL; e+=256){
    unsigned int c = (cw[e>>2] >> ((e&3)*8)) & 0xffu;
    unsigned int mul = c * 0x01010101u;
    int cnt = 0;
    const int nw = e >> 2;
    for (int wi=0; wi<nw; wi++){
      unsigned int v = cw[wi] ^ mul;
      unsigned int t1 = (v & 0x7f7f7f7fu) + 0x7f7f7f7fu;
      unsigned int z = ~(t1 | v) & 0x80808080u;
      cnt += __popc(z);
    }
    unsigned int lastw = cw[nw];
    const int nbp = e & 3;
    for (int bp=0; bp<nbp; bp++)
      if (((lastw >> (bp*8)) & 0xffu) == c) cnt++;
    int pos = (int)sbase[c] + cnt;
    int lx = s*SEGL + e;
    sortPos[ob + lx] = pos;
    srtIdx[ob + pos] = lx;
  }
}

// ---------------- pre-gather K -----------------------------------------------
__global__ __launch_bounds__(256) void k_gatherK(const float* __restrict__ xe,
    const int* __restrict__ srtIdx, unsigned short* __restrict__ Ksrt,
    float* __restrict__ normQ){
  const int idx = blockIdx.x*256 + threadIdx.x;
  if (idx >= NB*NHASH*LL) return;
  const int n = idx / (NHASH*LL);
  const int lk = srtIdx[idx];
  const float4* xr = (const float4*)&xe[((size_t)n*LL + lk)*16];
  float4 v0 = xr[0], v1 = xr[1], v2 = xr[2], v3 = xr[3];
  float f[16] = {v0.x,v0.y,v0.z,v0.w, v1.x,v1.y,v1.z,v1.w,
                 v2.x,v2.y,v2.z,v2.w, v3.x,v3.y,v3.z,v3.w};
  float ss = 0.f;
  #pragma unroll
  for (int i=0;i<16;i++) ss = fmaf(f[i], f[i], ss);
  const float nq = sqrtf(ss);
  normQ[idx] = nq;
  const float inv = 1.f / fmaxf(nq, 5e-5f);
  #pragma unroll
  for (int i=0;i<16;i++) f[i] *= inv;
  unsigned int kh[8], klo[8];
  #pragma unroll
  for (int i=0;i<8;i++) kh[i] = cvtpk_bf16(f[2*i], f[2*i+1]);
  #pragma unroll
  for (int i=0;i<8;i++)
    klo[i] = cvtpk_bf16(f[2*i] - bfl(kh[i]), f[2*i+1] - bfh(kh[i]));
  int4* kr = (int4*)(Ksrt + (size_t)idx*32);
  kr[0] = make_int4((int)kh[0],(int)kh[1],(int)kh[2],(int)kh[3]);
  kr[1] = make_int4((int)kh[4],(int)kh[5],(int)kh[6],(int)kh[7]);
  kr[2] = make_int4((int)klo[0],(int)klo[1],(int)klo[2],(int)klo[3]);
  kr[3] = make_int4((int)klo[4],(int)klo[5],(int)klo[6],(int)klo[7]);
}

// ---------------- attention (R5 structure; P rows 16B-aligned) ---------------
__global__ __launch_bounds__(576) void k_attn2(const unsigned short* __restrict__ yeB,
    const int* __restrict__ srtIdx, const unsigned short* __restrict__ Ksrt,
    const float* __restrict__ normQ, unsigned short* __restrict__ retS,
    float* __restrict__ bscore){
  extern __shared__ char smem[];
  char* Vt  = smem;
  char* Pst = Vt + VT_SZB;
  int* lkI  = (int*)(Pst + PST_SZB);

  const int t = threadIdx.x;
  const int k = blockIdx.x, hh = blockIdx.y, n = blockIdx.z;
  const size_t sb = ((size_t)n*NHASH + hh)*LL;
  const int l = t & 63, w = t >> 6;
  const int lq16 = l & 15, g = l >> 4;

  if (t < 432){
    const int c3 = t / CHK, jl = t - c3*CHK;
    const int kc = (c3==0) ? k : ((c3==1) ? ((k+NCHK-1)&(NCHK-1)) : ((k+1)&(NCHK-1)));
    lkI[t] = srtIdx[sb + (size_t)kc*CHK + jl];
  }
  if (t < 512){
    int c = t >> 3, jp = t & 7;
    *(unsigned int*)(Vt + c*V_ROWB + 864 + jp*4) = 0u;
  }
  __syncthreads();

  #pragma unroll 4
  for (int it=0; it<24; ++it){
    const int e = t + it*576;
    const int jp = e >> 6, c = e & 63;
    const unsigned int a = yeB[((size_t)n*LL + lkI[2*jp  ])*64 + c];
    const unsigned int b = yeB[((size_t)n*LL + lkI[2*jp+1])*64 + c];
    *(unsigned int*)(Vt + c*V_ROWB + jp*4) = a | (b << 16);
  }
  const int qg = w*16 + lq16;
  const int pq = k*CHK + qg;
  FragU b1, b2;
  const unsigned short* qrow = Ksrt + (sb + pq)*32;
  b1.i = *(const int4*)(qrow + (g&1)*8);
  if (g < 2) b2.i = *(const int4*)(qrow + 16 + (g&1)*8);
  else { b2.u[0]=0u; b2.u[1]=0u; b2.u[2]=0u; b2.u[3]=0u; }
  const float nq_ = normQ[sb + pq];
  const float msc = fmaxf(nq_, 5e-5f);
  __syncthreads();

  float sum = 0.f;
  f32x4 O0 = {0.f,0.f,0.f,0.f}, O1 = O0, O2 = O0, O3 = O0;
  char* Pw = Pst + w*(16*P_ROWB);
  for (int u=0; u<14; ++u){
    #pragma unroll
    for (int sub=0; sub<2; ++sub){
      const int t27 = u*2 + sub;
      uint2 pw;
      if (t27 < 27){
        const int c3 = t27 / 9;
        const int kc = (c3==0) ? k : ((c3==1) ? ((k+NCHK-1)&(NCHK-1)) : ((k+1)&(NCHK-1)));
        const int row16 = (t27 - c3*9)*16;
        FragU a; a.i = *(const int4*)(Ksrt + (sb + (size_t)kc*CHK + row16 + lq16)*32 + g*8);
        f32x4 C = {0.f,0.f,0.f,0.f};
        C = __builtin_amdgcn_mfma_f32_16x16x32_bf16(a.s, b2.s, C, 0, 0, 0);
        C = __builtin_amdgcn_mfma_f32_16x16x32_bf16(a.s, b1.s, C, 0, 0, 0);
        const float p0 = __expf(fmaf(msc, C[0], -nq_));
        const float p1 = __expf(fmaf(msc, C[1], -nq_));
        const float p2 = __expf(fmaf(msc, C[2], -nq_));
        const float p3 = __expf(fmaf(msc, C[3], -nq_));
        sum += (p0+p1) + (p2+p3);
        pw = make_uint2(cvtpk_bf16(p0,p1), cvtpk_bf16(p2,p3));
      } else {
        pw = make_uint2(0u, 0u);
      }
      *(uint2*)(Pw + lq16*P_ROWB + sub*32 + g*8) = pw;
    }
    asm volatile("s_waitcnt lgkmcnt(0)" ::: "memory");
    __builtin_amdgcn_sched_barrier(0);
    FragU bp; bp.i = *(const int4*)(Pw + lq16*P_ROWB + g*16);
    const char* Vb = Vt + lq16*V_ROWB + u*64 + g*16;
    FragU av;
    av.i = *(const int4*)(Vb);             O0 = __builtin_amdgcn_mfma_f32_16x16x32_bf16(av.s, bp.s, O0, 0,0,0);
    av.i = *(const int4*)(Vb + 16*V_ROWB); O1 = __builtin_amdgcn_mfma_f32_16x16x32_bf16(av.s, bp.s, O1, 0,0,0);
    av.i = *(const int4*)(Vb + 32*V_ROWB); O2 = __builtin_amdgcn_mfma_f32_16x16x32_bf16(av.s, bp.s, O2, 0,0,0);
    av.i = *(const int4*)(Vb + 48*V_ROWB); O3 = __builtin_amdgcn_mfma_f32_16x16x32_bf16(av.s, bp.s, O3, 0,0,0);
  }
  sum += __shfl_xor(sum, 16);
  sum += __shfl_xor(sum, 32);
  const float linv = 1.f / sum;

  unsigned short* op = &retS[(sb + pq)*64];
  {
    uint2 s0 = make_uint2(cvtpk_bf16(O0[0]*linv, O0[1]*linv), cvtpk_bf16(O0[2]*linv, O0[3]*linv));
    uint2 s1 = make_uint2(cvtpk_bf16(O1[0]*linv, O1[1]*linv), cvtpk_bf16(O1[2]*linv, O1[3]*linv));
    uint2 s2 = make_uint2(cvtpk_bf16(O2[0]*linv, O2[1]*linv), cvtpk_bf16(O2[2]*linv, O2[3]*linv));
    uint2 s3 = make_uint2(cvtpk_bf16(O3[0]*linv, O3[1]*linv), cvtpk_bf16(O3[2]*linv, O3[3]*linv));
    *(uint2*)(op +  0 + g*4) = s0;
    *(uint2*)(op + 16 + g*4) = s1;
    *(uint2*)(op + 32 + g*4) = s2;
    *(uint2*)(op + 48 + g*4) = s3;
  }
  if (g == 0) bscore[sb + pq] = nq_ + logf(sum);
}

// ---------------- unsort + hash-softmax combine + residual -------------------
__global__ __launch_bounds__(256) void k_combine(const unsigned short* __restrict__ retS,
    const float* __restrict__ bscore, const int* __restrict__ sortPos,
    const float* __restrict__ x2, float* __restrict__ out){
  const int idx = blockIdx.x*256 + threadIdx.x;
  if (idx >= NB*LL) return;
  const int l = idx % LL, n = idx / LL;
  float bs[NHASH]; int pp[NHASH];
  #pragma unroll
  for (int h=0;h<NHASH;h++){
    size_t sb = ((size_t)n*NHASH + h)*LL;
    int p = sortPos[sb + l];
    pp[h] = p; bs[h] = bscore[sb + p];
  }
  float m = fmaxf(fmaxf(bs[0],bs[1]), fmaxf(bs[2],bs[3]));
  float wsum = 0.f; float wv[NHASH];
  #pragma unroll
  for (int h=0;h<NHASH;h++){ wv[h] = expf(bs[h]-m); wsum += wv[h]; }
  const float winv = 1.f / wsum;
  float o[64];
  #pragma unroll
  for (int i=0;i<64;i++) o[i]=0.f;
  #pragma unroll
  for (int h=0;h<NHASH;h++){
    const float wh = wv[h]*winv;
    const uint4* rp = (const uint4*)&retS[(((size_t)n*NHASH + h)*LL + pp[h])*64];
    #pragma unroll
    for (int i2=0;i2<8;i2++){
      uint4 v = rp[i2];
      o[i2*8+0] = fmaf(wh, bfl(v.x), o[i2*8+0]);
      o[i2*8+1] = fmaf(wh, bfh(v.x), o[i2*8+1]);
      o[i2*8+2] = fmaf(wh, bfl(v.y), o[i2*8+2]);
      o[i2*8+3] = fmaf(wh, bfh(v.y), o[i2*8+3]);
      o[i2*8+4] = fmaf(wh, bfl(v.z), o[i2*8+4]);
      o[i2*8+5] = fmaf(wh, bfh(v.z), o[i2*8+5]);
      o[i2*8+6] = fmaf(wh, bfl(v.w), o[i2*8+6]);
      o[i2*8+7] = fmaf(wh, bfh(v.w), o[i2*8+7]);
    }
  }
  const float4* xr = (const float4*)&x2[((size_t)n*LL + l)*64];
  #pragma unroll
  for (int c4=0; c4<16; ++c4){
    float4 xv = xr[c4];
    out[((size_t)n*64 + c4*4+0)*LL + l] = o[c4*4+0] + xv.x;
    out[((size_t)n*64 + c4*4+1)*LL + l] = o[c4*4+1] + xv.y;
    out[((size_t)n*64 + c4*4+2)*LL + l] = o[c4*4+2] + xv.z;
    out[((size_t)n*64 + c4*4+3)*LL + l] = o[c4*4+3] + xv.w;
  }
}

extern "C" void kernel_launch(void* const* d_in, const int* in_sizes, int n_in,
                              void* d_out, int out_size, void* d_ws, size_t ws_size,
                              hipStream_t stream){
  const float* x   = (const float*)d_in[0];
  const float* w1  = (const float*)d_in[1];
  const float* b1  = (const float*)d_in[2];
  const float* w2  = (const float*)d_in[3];
  const float* b2  = (const float*)d_in[4];
  const float* wm  = (const float*)d_in[5];
  const float* bm  = (const float*)d_in[6];
  const float* wa  = (const float*)d_in[7];
  const float* ba  = (const float*)d_in[8];
  const float* rot = (const float*)d_in[9];
  float* outp = (float*)d_out;
  char* ws = (char*)d_ws;
  const size_t FM   = (size_t)NB*CIN*HH*WW*sizeof(float);
  const size_t YEB  = (size_t)NB*LL*64*2;
  const size_t RETB = (size_t)NB*NHASH*LL*64*2;
  const size_t NHL4 = (size_t)NB*NHASH*LL*4;

  char* p = ws;
  unsigned short* yeB = (unsigned short*)p;  p += YEB;
  char* regA = p;                            p += RETB;   // retS | pairA (xh0/xl0, xh2/xl2)
  float* x2  = (float*)p;                    p += FM;     // fp32 NLC64
  float* xe  = (float*)p;                    p += (size_t)NB*LL*CE*sizeof(float);
  unsigned char* codes = (unsigned char*)p;  p += (size_t)NB*NHASH*LL;
  unsigned int* segHist = (unsigned int*)p;  p += (size_t)NB*NHASH*NSEG*NBUCK*4;
  int* sortPos = (int*)p;                    p += NHL4;
  int* srtIdx  = (int*)p;                    p += NHL4;
  float* bscore = (float*)p;                 p += NHL4;
  unsigned short* wsT1 = (unsigned short*)p; p += (size_t)9*2*2*64*32*2;
  unsigned short* wsT2 = (unsigned short*)p; p += (size_t)9*2*2*64*32*2;
  unsigned short* wsTm = (unsigned short*)p; p += (size_t)9*2*2*16*32*2;
  unsigned short* Ksrt = (unsigned short*)p; p += (size_t)NB*NHASH*LL*32*2;  // | pairB
  float* normQ = (float*)p;                  p += NHL4;
  const size_t needT1 = (size_t)(p - ws);
  if (ws_size < needT1) return;

  unsigned short* retS = (unsigned short*)regA;
  unsigned short* pairA = (unsigned short*)regA;          // xh at +0, xl at +PS
  unsigned short* pairB = Ksrt;                           // spans Ksrt+normQ (fits)

  hipFuncSetAttribute((const void*)k_attn2,
                      hipFuncAttributeMaxDynamicSharedMemorySize, LDS_T1);
  hipFuncSetAttribute((const void*)k_conv3s<64,0>,
                      hipFuncAttributeMaxDynamicSharedMemorySize, CONV_LDS);
  hipFuncSetAttribute((const void*)k_conv3s<64,1>,
                      hipFuncAttributeMaxDynamicSharedMemorySize, CONV_LDS);
  hipFuncSetAttribute((const void*)k_conv3s<16,2>,
                      hipFuncAttributeMaxDynamicSharedMemorySize, CONV_LDS);

  k_prepw<<<dim3((64*64*9+255)/256), dim3(256), 0, stream>>>(w1, wsT1, 64);
  k_prepw<<<dim3((64*64*9+255)/256), dim3(256), 0, stream>>>(w2, wsT2, 64);
  k_prepw<<<dim3((16*64*9+255)/256), dim3(256), 0, stream>>>(wm, wsTm, 16);
  k_zerob<<<dim3((4*2*772*8+255)/256), dim3(256), 0, stream>>>(pairA, pairB);
  k_upsample2<<<dim3(WW/64, HH, NB), dim3(256), 0, stream>>>(x, pairA, pairA + PS);
  k_conv3s<64,0><<<dim3(3, HH/2, NB), dim3(256), CONV_LDS, stream>>>(
      pairA, pairA + PS, wsT1, b1, pairB, pairB + PS, nullptr);
  k_conv3s<64,1><<<dim3(3, HH/2, NB), dim3(256), CONV_LDS, stream>>>(
      pairB, pairB + PS, wsT2, b2, pairA, pairA + PS, x2);
  k_conv3s<16,2><<<dim3(3, HH/2, NB), dim3(256), CONV_LDS, stream>>>(
      pairA, pairA + PS, wsTm, bm, nullptr, nullptr, xe);
  k_conv1x1<<<dim3(LL/64, NB), dim3(256), 0, stream>>>(x2, wa, ba, yeB);
  k_codes<<<dim3(LL/128, NB), dim3(128), 0, stream>>>(xe, rot, codes);
  k_hist<<<dim3(NSEG, NHASH, NB), dim3(256), 0, stream>>>(codes, segHist);
  k_scan<<<dim3(NB*NHASH), dim3(128), 0, stream>>>(segHist);
  k_rank<<<dim3(NSEG, NHASH, NB), dim3(256), 0, stream>>>(codes, segHist, sortPos, srtIdx);
  k_gatherK<<<dim3((NB*NHASH*LL+255)/256), dim3(256), 0, stream>>>(xe, srtIdx, Ksrt, normQ);
  k_attn2<<<dim3(NCHK, NHASH, NB), dim3(576), LDS_T1, stream>>>(
      yeB, srtIdx, Ksrt, normQ, retS, bscore);
  k_combine<<<dim3((NB*LL+255)/256), dim3(256), 0, stream>>>(retS, bscore, sortPos, x2, outp);
}